// Round 4
// baseline (154.362 us; speedup 1.0000x reference)
//
#include <hip/hip_runtime.h>

// Problem constants (fixed by setup_inputs): Q=262144, L=H*W=512*512, C=128,
// window 4x4 -> N=16 keys, 4 heads x 32 dims. B=1.
// ws layout (floats): [0,2048) ksum[n][c], [2048,4096) vsum[n][c],
//                     [4096,6144) k2[h][n][d] (normalized*scale), [6144,8192) v2[h][n][d]

// ---------------- DPP / swizzle helpers ----------------
template <int CTRL>
__device__ __forceinline__ float dppf(float x) {
    return __int_as_float(
        __builtin_amdgcn_update_dpp(0, __float_as_int(x), CTRL, 0xF, 0xF, true));
}
// quad_perm [1,0,3,2] = xor1, [2,3,0,1] = xor2, ROW_HALF_MIRROR (0x141) = xor7 within 8
#define DPP_XOR1 0xB1
#define DPP_XOR2 0x4E
#define DPP_MIR8 0x141

template <int IMM>
__device__ __forceinline__ float swzf(float x) {
    return __int_as_float(__builtin_amdgcn_ds_swizzle(__float_as_int(x), IMM));
}

#define ADD4(A, B) { A.x += B.x; A.y += B.y; A.z += B.z; A.w += B.w; }

// async global->LDS, 16B per lane. LDS dest = wave-uniform base + lane*16.
__device__ __forceinline__ void gload_lds16(const float4* g, void* l) {
    __builtin_amdgcn_global_load_lds(
        (const __attribute__((address_space(1))) unsigned int*)(const void*)g,
        (__attribute__((address_space(3))) unsigned int*)l, 16, 0, 0);
}

// ---------------- kernel 1: strided mean reduction of k, v ----------------
// v4: global_load_lds staging (VGPR-free -> RA cannot serialize the pipeline;
// rounds 2-3 failed because register-held load pipelines got crushed to
// 36-44 VGPR and ~2 outstanding loads/wave).
// 2048 blocks x 256 thr. Blocks [0,1024) reduce k, rest v. Block bb covers
// float4 [bb*8192, bb*8192+8192) (contiguous 128KB). Each wave owns 32KB of
// that and a PRIVATE 2x4KB LDS double-buffer -> no barriers in the loop.
// 8 chunks: issue next chunk (4 x global_load_lds dwordx4), s_waitcnt
// vmcnt(4), consume current from LDS. 4-8KB in flight per wave, 16 waves/CU
// (40KB LDS/block -> 4 blocks/CU) => ~64-128KB in flight per CU.
__global__ __launch_bounds__(256) void k_reduce(const float4* __restrict__ k4,
                                                const float4* __restrict__ v4,
                                                float* __restrict__ ksum,
                                                float* __restrict__ vsum) {
    __shared__ float4 stage[2048];   // 4 waves * 2 bufs * 256 float4 = 32KB
    __shared__ float4 redE[256];     // 4KB
    __shared__ float4 redO[256];     // 4KB
    const int t = threadIdx.x;
    const int b = blockIdx.x;
    const bool isv = (b >= 1024);
    const int bb = b & 1023;
    const float4* __restrict__ src = isv ? v4 : k4;
    float* __restrict__ dst = isv ? vsum : ksum;

    const int wv = t >> 6;          // wave 0..3
    const int ln = t & 63;          // lane
    const long gstart = (long)bb * 8192 + wv * 2048;
    const float4* gsrc = src + gstart + ln;          // per-lane global base
    char* lbase = (char*)stage + wv * 8192;          // wave-uniform LDS base

    // prologue: chunk 0 -> buf 0
#pragma unroll
    for (int j = 0; j < 4; ++j)
        gload_lds16(gsrc + j * 64, lbase + j * 1024);

    float4 z = make_float4(0.f, 0.f, 0.f, 0.f);
    float4 accE = z, accO = z;   // j even -> window-col class ln>>5; j odd -> 2+(ln>>5)

#pragma unroll
    for (int c = 0; c < 8; ++c) {
        if (c < 7) {
            const int p1 = (c + 1) & 1;
#pragma unroll
            for (int j = 0; j < 4; ++j)
                gload_lds16(gsrc + (c + 1) * 256 + j * 64,
                            lbase + p1 * 4096 + j * 1024);
            asm volatile("s_waitcnt vmcnt(4)" ::: "memory");
        } else {
            asm volatile("s_waitcnt vmcnt(0)" ::: "memory");
        }
        __builtin_amdgcn_sched_barrier(0);
        const int p = c & 1;
        const float4* lf = (const float4*)(lbase + p * 4096) + ln;
        const float4 x0 = lf[0];
        const float4 x1 = lf[64];
        const float4 x2 = lf[128];
        const float4 x3 = lf[192];
        ADD4(accE, x0); ADD4(accO, x1); ADD4(accE, x2); ADD4(accO, x3);
    }

    // cross-wave reduction of the 4 copies per (window-col class, channel-quad)
    redE[wv * 64 + ln] = accE;
    redO[wv * 64 + ln] = accO;
    __syncthreads();

    if (t < 128) {
        const int n0 = t >> 5;       // window-col class 0..3
        const int c4 = t & 31;       // channel quad
        const float4* arr = (n0 < 2) ? redE : redO;
        const int base = (n0 & 1) * 32 + c4;
        float4 s = arr[base];
        const float4 s1 = arr[base + 64];
        const float4 s2 = arr[base + 128];
        const float4 s3 = arr[base + 192];
        ADD4(s, s1); ADD4(s, s2); ADD4(s, s3);
        const int n = ((bb >> 1) & 3) * 4 + n0;   // (row%4)*4 + col%4
        const int c = c4 * 4;
        atomicAdd(&dst[n * 128 + c + 0], s.x);
        atomicAdd(&dst[n * 128 + c + 1], s.y);
        atomicAdd(&dst[n * 128 + c + 2], s.z);
        atomicAdd(&dst[n * 128 + c + 3], s.w);
    }
}

// ---------------- kernel 1.5: mean, normalize K, fold scale, reorganize ----------------
__global__ __launch_bounds__(256) void k_prep(const float* __restrict__ ksum,
                                              const float* __restrict__ vsum,
                                              const float* __restrict__ logit_scale,
                                              float* __restrict__ k2,
                                              float* __restrict__ v2) {
    __shared__ float mk[2048], mv[2048], fac[64];
    const int t = threadIdx.x;
    const float inv = 1.0f / 16384.0f;
    for (int w = t; w < 2048; w += 256) {
        mk[w] = ksum[w] * inv;
        mv[w] = vsum[w] * inv;
    }
    __syncthreads();
    if (t < 64) {
        const int h = t >> 4, n = t & 15;
        float ss = 0.f;
#pragma unroll
        for (int d = 0; d < 32; ++d) {
            float x = mk[n * 128 + h * 32 + d];
            ss += x * x;
        }
        const float nrm = sqrtf(ss);
        const float sc = __expf(fminf(logit_scale[h], 4.6051702f)); // log(1/0.01)
        fac[t] = sc / fmaxf(nrm, 1e-12f);
    }
    __syncthreads();
    for (int w = t; w < 2048; w += 256) {
        const int h = w >> 9;
        const int n = (w & 511) >> 5;
        const int d = w & 31;
        const float f = fac[h * 16 + n];
        k2[w] = mk[n * 128 + h * 32 + d] * f;
        v2[w] = mv[n * 128 + h * 32 + d];
    }
}

// ---------------- kernel 2: per-query attention (at HBM roofline - unchanged) ----
// 32 threads per query: (head h = (t&31)>>3, d-quad g = t&7). 256 thr = 8 q-groups.
// K,V fragments live in registers for the whole kernel. Cross-lane via DPP (VALU path).
// 2 queries per iteration (i, i+8) -> 2 independent dep-chains per wave;
// branchless depth-1 prefetch of the next pair.
__global__ __launch_bounds__(256, 2) void k_attn(const float4* __restrict__ q4,
                                                 const float2* __restrict__ mask2,
                                                 const float4* __restrict__ k2f4,
                                                 const float4* __restrict__ v2f4,
                                                 float4* __restrict__ out4) {
    const int t = threadIdx.x;
    const int isub = t >> 5;       // 0..7
    const int l5 = t & 31;
    const int h = l5 >> 3;         // head
    const int g = l5 & 7;          // d-quad within head

    // preload K,V fragments: k2f4[h][n][g] for all n
    float4 kreg[16], vreg[16];
#pragma unroll
    for (int n = 0; n < 16; ++n) {
        kreg[n] = k2f4[h * 128 + n * 8 + g];
        vreg[n] = v2f4[h * 128 + n * 8 + g];
    }

    const bool b2 = (g & 4) != 0;
    const bool b1 = (g & 2) != 0;
    const bool b0 = (g & 1) != 0;

    auto process = [&](const float4 qv, const float2 mw) -> float4 {
        // ---- normalize q over the 32-dim head (8 lanes x 4) ----
        float ss = qv.x * qv.x + qv.y * qv.y + qv.z * qv.z + qv.w * qv.w;
        ss += dppf<DPP_XOR1>(ss);
        ss += dppf<DPP_XOR2>(ss);
        ss += dppf<DPP_MIR8>(ss);
        const float rn = rsqrtf(fmaxf(ss, 1e-24f));
        const float qx = qv.x * rn, qy = qv.y * rn, qz = qv.z * rn, qw = qv.w * rn;

        // ---- QK partial dots (scale folded into kreg) ----
        float part[16];
#pragma unroll
        for (int n = 0; n < 16; ++n)
            part[n] = qx * kreg[n].x + qy * kreg[n].y + qz * kreg[n].z + qw * kreg[n].w;

        // ---- reduce-scatter 16 values over 8 lanes: lane g ends with s[2g],s[2g+1] ----
        float r8[8];
#pragma unroll
        for (int j = 0; j < 8; ++j) {
            const float snd = b2 ? part[j] : part[j + 8];
            const float kp  = b2 ? part[j + 8] : part[j];
            r8[j] = kp + dppf<DPP_MIR8>(snd);
        }
        float r4[4];
#pragma unroll
        for (int j = 0; j < 4; ++j) {
            const float snd = b1 ? r8[j] : r8[j + 4];
            const float kp  = b1 ? r8[j + 4] : r8[j];
            r4[j] = kp + dppf<DPP_XOR2>(snd);
        }
        float s0, s1;
        {
            const float sndA = b0 ? r4[0] : r4[2];
            const float kpA  = b0 ? r4[2] : r4[0];
            s0 = kpA + dppf<DPP_XOR1>(sndA);
            const float sndB = b0 ? r4[1] : r4[3];
            const float kpB  = b0 ? r4[3] : r4[1];
            s1 = kpB + dppf<DPP_XOR1>(sndB);
        }

        // ---- logits + exp (no max-sub needed: |logit| <= ~10.5) ----
        const float e0 = __expf(s0 + mw.x);
        const float e1 = __expf(s1 + mw.y);

        // ---- denominator: sum of all 16 e's across the 8 lanes ----
        float ds = e0 + e1;
        ds += dppf<DPP_XOR1>(ds);
        ds += dppf<DPP_XOR2>(ds);
        ds += dppf<DPP_MIR8>(ds);
        const float rden = 1.0f / ds;

        // ---- gather unnormalized p[n] from lane n>>1 of this 8-group ----
        float pf[16];
        pf[0]  = swzf<(0 << 5) | 0x18>(e0);
        pf[1]  = swzf<(0 << 5) | 0x18>(e1);
        pf[2]  = swzf<(1 << 5) | 0x18>(e0);
        pf[3]  = swzf<(1 << 5) | 0x18>(e1);
        pf[4]  = swzf<(2 << 5) | 0x18>(e0);
        pf[5]  = swzf<(2 << 5) | 0x18>(e1);
        pf[6]  = swzf<(3 << 5) | 0x18>(e0);
        pf[7]  = swzf<(3 << 5) | 0x18>(e1);
        pf[8]  = swzf<(4 << 5) | 0x18>(e0);
        pf[9]  = swzf<(4 << 5) | 0x18>(e1);
        pf[10] = swzf<(5 << 5) | 0x18>(e0);
        pf[11] = swzf<(5 << 5) | 0x18>(e1);
        pf[12] = swzf<(6 << 5) | 0x18>(e0);
        pf[13] = swzf<(6 << 5) | 0x18>(e1);
        pf[14] = swzf<(7 << 5) | 0x18>(e0);
        pf[15] = swzf<(7 << 5) | 0x18>(e1);

        // ---- PV ----
        float ox = 0.f, oy = 0.f, oz = 0.f, ow = 0.f;
#pragma unroll
        for (int n = 0; n < 16; ++n) {
            ox += pf[n] * vreg[n].x;
            oy += pf[n] * vreg[n].y;
            oz += pf[n] * vreg[n].z;
            ow += pf[n] * vreg[n].w;
        }
        return make_float4(ox * rden, oy * rden, oz * rden, ow * rden);
    };

    int i = blockIdx.x * 128 + isub;   // queries i and i+8 per iter, stride 16
    float4 qA = q4[i * 32 + h * 8 + g];
    float4 qB = q4[(i + 8) * 32 + h * 8 + g];
    float2 mA = mask2[i * 8 + g];
    float2 mB = mask2[(i + 8) * 8 + g];

#pragma unroll 1
    for (int iter = 0; iter < 8; ++iter) {
        const int ip = (iter < 7) ? (i + 16) : i;   // branchless prefetch (clamped)
        const float4 qA_n = q4[ip * 32 + h * 8 + g];
        const float4 qB_n = q4[(ip + 8) * 32 + h * 8 + g];
        const float2 mA_n = mask2[ip * 8 + g];
        const float2 mB_n = mask2[(ip + 8) * 8 + g];

        const float4 oA = process(qA, mA);
        const float4 oB = process(qB, mB);
        out4[i * 32 + h * 8 + g] = oA;
        out4[(i + 8) * 32 + h * 8 + g] = oB;

        i += 16;
        qA = qA_n; qB = qB_n; mA = mA_n; mB = mB_n;
    }
}

extern "C" void kernel_launch(void* const* d_in, const int* in_sizes, int n_in,
                              void* d_out, int out_size, void* d_ws, size_t ws_size,
                              hipStream_t stream) {
    (void)in_sizes; (void)n_in; (void)out_size; (void)ws_size;
    const float* q = (const float*)d_in[0];
    const float* k = (const float*)d_in[1];
    const float* v = (const float*)d_in[2];
    const float* mask = (const float*)d_in[5];
    const float* ls = (const float*)d_in[6];

    float* ws = (float*)d_ws;
    float* ksum = ws;
    float* vsum = ws + 2048;
    float* k2 = ws + 4096;
    float* v2 = ws + 6144;

    hipMemsetAsync(ws, 0, 4096 * sizeof(float), stream);
    k_reduce<<<2048, 256, 0, stream>>>((const float4*)k, (const float4*)v, ksum, vsum);
    k_prep<<<1, 256, 0, stream>>>(ksum, vsum, ls, k2, v2);
    k_attn<<<2048, 256, 0, stream>>>((const float4*)q, (const float2*)mask,
                                     (const float4*)k2, (const float4*)v2,
                                     (float4*)d_out);
}

// Round 5
// 139.837 us; speedup vs baseline: 1.1039x; 1.1039x over previous
//
#include <hip/hip_runtime.h>

// Problem constants (fixed by setup_inputs): Q=262144, L=H*W=512*512, C=128,
// window 4x4 -> N=16 keys, 4 heads x 32 dims. B=1.
// ws layout (floats): [0,2048) ksum[n][c], [2048,4096) vsum[n][c],
//                     [4096,6144) k2[h][n][d] (normalized*scale), [6144,8192) v2[h][n][d],
//                     [8192, 8192+1048576) partials p4[src][pi][t] (4MB, two-phase path)

// ---------------- DPP / swizzle helpers ----------------
template <int CTRL>
__device__ __forceinline__ float dppf(float x) {
    return __int_as_float(
        __builtin_amdgcn_update_dpp(0, __float_as_int(x), CTRL, 0xF, 0xF, true));
}
#define DPP_XOR1 0xB1
#define DPP_XOR2 0x4E
#define DPP_MIR8 0x141

template <int IMM>
__device__ __forceinline__ float swzf(float x) {
    return __int_as_float(__builtin_amdgcn_ds_swizzle(__float_as_int(x), IMM));
}

#define ADD4(A, B) { A.x += B.x; A.y += B.y; A.z += B.z; A.w += B.w; }

// async global->LDS, 16B per lane. LDS dest = wave-uniform base + lane*16.
__device__ __forceinline__ void gload_lds16(const float4* g, void* l) {
    __builtin_amdgcn_global_load_lds(
        (const __attribute__((address_space(1))) unsigned int*)(const void*)g,
        (__attribute__((address_space(3))) unsigned int*)l, 16, 0, 0);
}

// ---------------- kernel 1 phase 1: strided mean reduction of k, v ----------------
// v5: same read pipeline as v4 (global_load_lds, private per-wave double buffer,
// counted vmcnt) but NO ATOMICS: rounds 1-4 all issued ~1M memory-side fp32
// atomic RMWs into 16KB (WRITE_SIZE=16MB for a 16KB output = smoking gun) and
// all landed at 92-109us regardless of read structure. Partials go to ws as
// coalesced float4 stores; k_reduce_p2 reduces them with plain stores.
__global__ __launch_bounds__(256) void k_reduce_p1(const float4* __restrict__ k4,
                                                   const float4* __restrict__ v4,
                                                   float4* __restrict__ p4) {
    __shared__ float4 stage[2048];   // 4 waves * 2 bufs * 256 float4 = 32KB
    __shared__ float4 redE[256];     // 4KB
    __shared__ float4 redO[256];     // 4KB
    const int t = threadIdx.x;
    const int b = blockIdx.x;
    const bool isv = (b >= 1024);
    const int bb = b & 1023;
    const float4* __restrict__ src = isv ? v4 : k4;

    const int wv = t >> 6;          // wave 0..3
    const int ln = t & 63;          // lane
    const long gstart = (long)bb * 8192 + wv * 2048;
    const float4* gsrc = src + gstart + ln;          // per-lane global base
    char* lbase = (char*)stage + wv * 8192;          // wave-uniform LDS base

    // prologue: chunk 0 -> buf 0
#pragma unroll
    for (int j = 0; j < 4; ++j)
        gload_lds16(gsrc + j * 64, lbase + j * 1024);

    float4 z = make_float4(0.f, 0.f, 0.f, 0.f);
    float4 accE = z, accO = z;   // q even -> window-col class ln>>5; q odd -> 2+(ln>>5)

#pragma unroll
    for (int c = 0; c < 8; ++c) {
        if (c < 7) {
            const int p1 = (c + 1) & 1;
#pragma unroll
            for (int j = 0; j < 4; ++j)
                gload_lds16(gsrc + (c + 1) * 256 + j * 64,
                            lbase + p1 * 4096 + j * 1024);
            asm volatile("s_waitcnt vmcnt(4)" ::: "memory");
        } else {
            asm volatile("s_waitcnt vmcnt(0)" ::: "memory");
        }
        __builtin_amdgcn_sched_barrier(0);
        const int p = c & 1;
        const float4* lf = (const float4*)(lbase + p * 4096) + ln;
        const float4 x0 = lf[0];
        const float4 x1 = lf[64];
        const float4 x2 = lf[128];
        const float4 x3 = lf[192];
        ADD4(accE, x0); ADD4(accO, x1); ADD4(accE, x2); ADD4(accO, x3);
    }

    // cross-wave combine: redE/redO[wv*64 + cls*32 + c4]
    redE[wv * 64 + ln] = accE;
    redO[wv * 64 + ln] = accO;
    __syncthreads();

    if (t < 128) {
        const int n0 = t >> 5;       // window-col class 0..3
        const int c4 = t & 31;       // channel quad
        const float4* arr = (n0 < 2) ? redE : redO;
        const int base = (n0 & 1) * 32 + c4;
        float4 s = arr[base];
        const float4 s1 = arr[base + 64];
        const float4 s2 = arr[base + 128];
        const float4 s3 = arr[base + 192];
        ADD4(s, s1); ADD4(s, s2); ADD4(s, s3);
        // permuted position: pi = nh*256 + g*2 + half  (nh=(bb>>1)&3, g=bb>>3, half=bb&1)
        const int pi = ((bb >> 1) & 3) * 256 + (bb >> 3) * 2 + (bb & 1);
        p4[(isv ? 131072 : 0) + pi * 128 + t] = s;   // coalesced 128-float4 block store
    }
}

// ---------------- kernel 1 phase 2: reduce partials (no atomics) ----------------
// 256 blocks x 256 thr. beta = src*128 + t (t = n0*32+c4). Wave wv handles
// nh=wv: lane sums 4 partials, shfl_xor wave-reduce, lane 0 plain-stores
// ksum/vsum[n*128 + c] with n = wv*4 + n0.
__global__ __launch_bounds__(256) void k_reduce_p2(const float4* __restrict__ p4,
                                                   float4* __restrict__ ksum4,
                                                   float4* __restrict__ vsum4) {
    const int beta = blockIdx.x;
    const int srcv = beta >> 7;
    const int t = beta & 127;
    const int n0 = t >> 5;
    const int wv = threadIdx.x >> 6;   // = nh
    const int ln = threadIdx.x & 63;

    const float4* base = p4 + srcv * 131072 + (wv * 256) * 128 + t;
    float4 s = base[(ln) * 128];
    const float4 s1 = base[(ln + 64) * 128];
    const float4 s2 = base[(ln + 128) * 128];
    const float4 s3 = base[(ln + 192) * 128];
    ADD4(s, s1); ADD4(s, s2); ADD4(s, s3);

#pragma unroll
    for (int m = 1; m < 64; m <<= 1) {
        s.x += __shfl_xor(s.x, m, 64);
        s.y += __shfl_xor(s.y, m, 64);
        s.z += __shfl_xor(s.z, m, 64);
        s.w += __shfl_xor(s.w, m, 64);
    }
    if (ln == 0) {
        float4* dst = srcv ? vsum4 : ksum4;
        const int n = wv * 4 + n0;
        dst[n * 32 + (t & 31)] = s;
    }
}

// ---------------- fallback (ws too small): v4 atomic version ----------------
__global__ __launch_bounds__(256) void k_reduce_atomic(const float4* __restrict__ k4,
                                                       const float4* __restrict__ v4,
                                                       float* __restrict__ ksum,
                                                       float* __restrict__ vsum) {
    __shared__ float4 stage[2048];
    __shared__ float4 redE[256];
    __shared__ float4 redO[256];
    const int t = threadIdx.x;
    const int b = blockIdx.x;
    const bool isv = (b >= 1024);
    const int bb = b & 1023;
    const float4* __restrict__ src = isv ? v4 : k4;
    float* __restrict__ dst = isv ? vsum : ksum;

    const int wv = t >> 6;
    const int ln = t & 63;
    const long gstart = (long)bb * 8192 + wv * 2048;
    const float4* gsrc = src + gstart + ln;
    char* lbase = (char*)stage + wv * 8192;

#pragma unroll
    for (int j = 0; j < 4; ++j)
        gload_lds16(gsrc + j * 64, lbase + j * 1024);

    float4 z = make_float4(0.f, 0.f, 0.f, 0.f);
    float4 accE = z, accO = z;

#pragma unroll
    for (int c = 0; c < 8; ++c) {
        if (c < 7) {
            const int p1 = (c + 1) & 1;
#pragma unroll
            for (int j = 0; j < 4; ++j)
                gload_lds16(gsrc + (c + 1) * 256 + j * 64,
                            lbase + p1 * 4096 + j * 1024);
            asm volatile("s_waitcnt vmcnt(4)" ::: "memory");
        } else {
            asm volatile("s_waitcnt vmcnt(0)" ::: "memory");
        }
        __builtin_amdgcn_sched_barrier(0);
        const int p = c & 1;
        const float4* lf = (const float4*)(lbase + p * 4096) + ln;
        const float4 x0 = lf[0];
        const float4 x1 = lf[64];
        const float4 x2 = lf[128];
        const float4 x3 = lf[192];
        ADD4(accE, x0); ADD4(accO, x1); ADD4(accE, x2); ADD4(accO, x3);
    }

    redE[wv * 64 + ln] = accE;
    redO[wv * 64 + ln] = accO;
    __syncthreads();

    if (t < 128) {
        const int n0 = t >> 5;
        const int c4 = t & 31;
        const float4* arr = (n0 < 2) ? redE : redO;
        const int base = (n0 & 1) * 32 + c4;
        float4 s = arr[base];
        const float4 s1 = arr[base + 64];
        const float4 s2 = arr[base + 128];
        const float4 s3 = arr[base + 192];
        ADD4(s, s1); ADD4(s, s2); ADD4(s, s3);
        const int n = ((bb >> 1) & 3) * 4 + n0;
        const int c = c4 * 4;
        atomicAdd(&dst[n * 128 + c + 0], s.x);
        atomicAdd(&dst[n * 128 + c + 1], s.y);
        atomicAdd(&dst[n * 128 + c + 2], s.z);
        atomicAdd(&dst[n * 128 + c + 3], s.w);
    }
}

// ---------------- kernel 1.5: mean, normalize K, fold scale, reorganize ----------------
__global__ __launch_bounds__(256) void k_prep(const float* __restrict__ ksum,
                                              const float* __restrict__ vsum,
                                              const float* __restrict__ logit_scale,
                                              float* __restrict__ k2,
                                              float* __restrict__ v2) {
    __shared__ float mk[2048], mv[2048], fac[64];
    const int t = threadIdx.x;
    const float inv = 1.0f / 16384.0f;
    for (int w = t; w < 2048; w += 256) {
        mk[w] = ksum[w] * inv;
        mv[w] = vsum[w] * inv;
    }
    __syncthreads();
    if (t < 64) {
        const int h = t >> 4, n = t & 15;
        float ss = 0.f;
#pragma unroll
        for (int d = 0; d < 32; ++d) {
            float x = mk[n * 128 + h * 32 + d];
            ss += x * x;
        }
        const float nrm = sqrtf(ss);
        const float sc = __expf(fminf(logit_scale[h], 4.6051702f)); // log(1/0.01)
        fac[t] = sc / fmaxf(nrm, 1e-12f);
    }
    __syncthreads();
    for (int w = t; w < 2048; w += 256) {
        const int h = w >> 9;
        const int n = (w & 511) >> 5;
        const int d = w & 31;
        const float f = fac[h * 16 + n];
        k2[w] = mk[n * 128 + h * 32 + d] * f;
        v2[w] = mv[n * 128 + h * 32 + d];
    }
}

// ---------------- kernel 2: per-query attention (at HBM roofline - unchanged) ----
__global__ __launch_bounds__(256, 2) void k_attn(const float4* __restrict__ q4,
                                                 const float2* __restrict__ mask2,
                                                 const float4* __restrict__ k2f4,
                                                 const float4* __restrict__ v2f4,
                                                 float4* __restrict__ out4) {
    const int t = threadIdx.x;
    const int isub = t >> 5;       // 0..7
    const int l5 = t & 31;
    const int h = l5 >> 3;         // head
    const int g = l5 & 7;          // d-quad within head

    float4 kreg[16], vreg[16];
#pragma unroll
    for (int n = 0; n < 16; ++n) {
        kreg[n] = k2f4[h * 128 + n * 8 + g];
        vreg[n] = v2f4[h * 128 + n * 8 + g];
    }

    const bool b2 = (g & 4) != 0;
    const bool b1 = (g & 2) != 0;
    const bool b0 = (g & 1) != 0;

    auto process = [&](const float4 qv, const float2 mw) -> float4 {
        float ss = qv.x * qv.x + qv.y * qv.y + qv.z * qv.z + qv.w * qv.w;
        ss += dppf<DPP_XOR1>(ss);
        ss += dppf<DPP_XOR2>(ss);
        ss += dppf<DPP_MIR8>(ss);
        const float rn = rsqrtf(fmaxf(ss, 1e-24f));
        const float qx = qv.x * rn, qy = qv.y * rn, qz = qv.z * rn, qw = qv.w * rn;

        float part[16];
#pragma unroll
        for (int n = 0; n < 16; ++n)
            part[n] = qx * kreg[n].x + qy * kreg[n].y + qz * kreg[n].z + qw * kreg[n].w;

        float r8[8];
#pragma unroll
        for (int j = 0; j < 8; ++j) {
            const float snd = b2 ? part[j] : part[j + 8];
            const float kp  = b2 ? part[j + 8] : part[j];
            r8[j] = kp + dppf<DPP_MIR8>(snd);
        }
        float r4[4];
#pragma unroll
        for (int j = 0; j < 4; ++j) {
            const float snd = b1 ? r8[j] : r8[j + 4];
            const float kp  = b1 ? r8[j + 4] : r8[j];
            r4[j] = kp + dppf<DPP_XOR2>(snd);
        }
        float s0, s1;
        {
            const float sndA = b0 ? r4[0] : r4[2];
            const float kpA  = b0 ? r4[2] : r4[0];
            s0 = kpA + dppf<DPP_XOR1>(sndA);
            const float sndB = b0 ? r4[1] : r4[3];
            const float kpB  = b0 ? r4[3] : r4[1];
            s1 = kpB + dppf<DPP_XOR1>(sndB);
        }

        const float e0 = __expf(s0 + mw.x);
        const float e1 = __expf(s1 + mw.y);

        float ds = e0 + e1;
        ds += dppf<DPP_XOR1>(ds);
        ds += dppf<DPP_XOR2>(ds);
        ds += dppf<DPP_MIR8>(ds);
        const float rden = 1.0f / ds;

        float pf[16];
        pf[0]  = swzf<(0 << 5) | 0x18>(e0);
        pf[1]  = swzf<(0 << 5) | 0x18>(e1);
        pf[2]  = swzf<(1 << 5) | 0x18>(e0);
        pf[3]  = swzf<(1 << 5) | 0x18>(e1);
        pf[4]  = swzf<(2 << 5) | 0x18>(e0);
        pf[5]  = swzf<(2 << 5) | 0x18>(e1);
        pf[6]  = swzf<(3 << 5) | 0x18>(e0);
        pf[7]  = swzf<(3 << 5) | 0x18>(e1);
        pf[8]  = swzf<(4 << 5) | 0x18>(e0);
        pf[9]  = swzf<(4 << 5) | 0x18>(e1);
        pf[10] = swzf<(5 << 5) | 0x18>(e0);
        pf[11] = swzf<(5 << 5) | 0x18>(e1);
        pf[12] = swzf<(6 << 5) | 0x18>(e0);
        pf[13] = swzf<(6 << 5) | 0x18>(e1);
        pf[14] = swzf<(7 << 5) | 0x18>(e0);
        pf[15] = swzf<(7 << 5) | 0x18>(e1);

        float ox = 0.f, oy = 0.f, oz = 0.f, ow = 0.f;
#pragma unroll
        for (int n = 0; n < 16; ++n) {
            ox += pf[n] * vreg[n].x;
            oy += pf[n] * vreg[n].y;
            oz += pf[n] * vreg[n].z;
            ow += pf[n] * vreg[n].w;
        }
        return make_float4(ox * rden, oy * rden, oz * rden, ow * rden);
    };

    int i = blockIdx.x * 128 + isub;   // queries i and i+8 per iter, stride 16
    float4 qA = q4[i * 32 + h * 8 + g];
    float4 qB = q4[(i + 8) * 32 + h * 8 + g];
    float2 mA = mask2[i * 8 + g];
    float2 mB = mask2[(i + 8) * 8 + g];

#pragma unroll 1
    for (int iter = 0; iter < 8; ++iter) {
        const int ip = (iter < 7) ? (i + 16) : i;   // branchless prefetch (clamped)
        const float4 qA_n = q4[ip * 32 + h * 8 + g];
        const float4 qB_n = q4[(ip + 8) * 32 + h * 8 + g];
        const float2 mA_n = mask2[ip * 8 + g];
        const float2 mB_n = mask2[(ip + 8) * 8 + g];

        const float4 oA = process(qA, mA);
        const float4 oB = process(qB, mB);
        out4[i * 32 + h * 8 + g] = oA;
        out4[(i + 8) * 32 + h * 8 + g] = oB;

        i += 16;
        qA = qA_n; qB = qB_n; mA = mA_n; mB = mB_n;
    }
}

extern "C" void kernel_launch(void* const* d_in, const int* in_sizes, int n_in,
                              void* d_out, int out_size, void* d_ws, size_t ws_size,
                              hipStream_t stream) {
    (void)in_sizes; (void)n_in; (void)out_size;
    const float* q = (const float*)d_in[0];
    const float* k = (const float*)d_in[1];
    const float* v = (const float*)d_in[2];
    const float* mask = (const float*)d_in[5];
    const float* ls = (const float*)d_in[6];

    float* ws = (float*)d_ws;
    float* ksum = ws;
    float* vsum = ws + 2048;
    float* k2 = ws + 4096;
    float* v2 = ws + 6144;
    float* part = ws + 8192;   // 262144 float4 = 4MB

    const size_t needed = (size_t)8192 * 4 + (size_t)262144 * 16;
    if (ws_size >= needed) {
        // two-phase, atomic-free path
        k_reduce_p1<<<2048, 256, 0, stream>>>((const float4*)k, (const float4*)v,
                                              (float4*)part);
        k_reduce_p2<<<256, 256, 0, stream>>>((const float4*)part,
                                             (float4*)ksum, (float4*)vsum);
    } else {
        hipMemsetAsync(ws, 0, 4096 * sizeof(float), stream);
        k_reduce_atomic<<<2048, 256, 0, stream>>>((const float4*)k, (const float4*)v,
                                                  ksum, vsum);
    }
    k_prep<<<1, 256, 0, stream>>>(ksum, vsum, ls, k2, v2);
    k_attn<<<2048, 256, 0, stream>>>((const float4*)q, (const float2*)mask,
                                     (const float4*)k2, (const float4*)v2,
                                     (float4*)d_out);
}

// Round 6
// 134.817 us; speedup vs baseline: 1.1450x; 1.0372x over previous
//
#include <hip/hip_runtime.h>

// Problem constants (fixed by setup_inputs): Q=262144, L=H*W=512*512, C=128,
// window 4x4 -> N=16 keys, 4 heads x 32 dims. B=1.
// ws layout (floats): [0,2048) ksum[n][c], [2048,4096) vsum[n][c],
//                     [4096,6144) k2[h][n][d] (normalized*scale), [6144,8192) v2[h][n][d],
//                     [8192, 8192+1048576) partials p4[src][pi][t] (4MB, two-phase path)

// ---------------- DPP / swizzle helpers ----------------
template <int CTRL>
__device__ __forceinline__ float dppf(float x) {
    return __int_as_float(
        __builtin_amdgcn_update_dpp(0, __float_as_int(x), CTRL, 0xF, 0xF, true));
}
#define DPP_XOR1 0xB1
#define DPP_XOR2 0x4E
#define DPP_MIR8 0x141

template <int IMM>
__device__ __forceinline__ float swzf(float x) {
    return __int_as_float(__builtin_amdgcn_ds_swizzle(__float_as_int(x), IMM));
}

#define ADD4(A, B) { A.x += B.x; A.y += B.y; A.z += B.z; A.w += B.w; }

// raw plain load: compiler cannot serialize, shrink, or reorder these.
// base is wave-uniform (SGPR pair), vo is per-lane byte offset (VGPR).
#define GLOAD4(dst, base, vo) \
    asm volatile("global_load_dwordx4 %0, %1, %2" \
                 : "=v"(dst) : "v"(vo), "s"(base) : "memory")
#define WAITV(n) asm volatile("s_waitcnt vmcnt(" #n ")" ::: "memory")
#define SBAR() __builtin_amdgcn_sched_barrier(0)

// async global->LDS (fallback kernel only)
__device__ __forceinline__ void gload_lds16(const float4* g, void* l) {
    __builtin_amdgcn_global_load_lds(
        (const __attribute__((address_space(1))) unsigned int*)(const void*)g,
        (__attribute__((address_space(3))) unsigned int*)l, 16, 0, 0);
}

// ---------------- kernel 1 phase 1: strided mean reduction of k, v ----------------
// v6: inline-asm plain-load pipeline (k_attn's winning recipe, forced).
// Evidence: R1-R5 all cap at ~2.8 TB/s read-only -- including a fully
// L3-resident dispatch (hbm~0, same 96us) -- while k_attn sustains ~3.5 TB/s
// reads concurrently with 3.1 TB/s writes. Compiler serialized R1-R3
// (VGPR 36-44); R4-R5 used the global_load_lds DMA path. Here: 16 asm
// global_load_dwordx4 in flight per wave, counted vmcnt(8), sched_barrier
// so adds can't float above the wait. ~100 VGPR, launch_bounds(256,1).
// Block bb covers float4 [bb*8192, (bb+1)*8192). Thread t reads t + j*256,
// j=0..31. Class is static per thread: col%4 = (t>>5)&3, row%4 = (bb>>1)&3.
__global__ __launch_bounds__(256, 1) void k_reduce_p1(const float4* __restrict__ k4,
                                                      const float4* __restrict__ v4,
                                                      float4* __restrict__ p4) {
    __shared__ float4 red[256];
    const int t = threadIdx.x;
    const int b = blockIdx.x;
    const bool isv = (b >= 1024);
    const int bb = b & 1023;
    const float4* __restrict__ src = (isv ? v4 : k4) + (long)bb * 8192;

    const unsigned vbase = (unsigned)t * 16u;   // byte offset of f4 index t
    float4 a0, a1, a2, a3, a4, a5, a6, a7;      // group A
    float4 b0, b1, b2, b3, b4, b5, b6, b7;      // group B
    float4 z = make_float4(0.f, 0.f, 0.f, 0.f);
    float4 acc0 = z, acc1 = z, acc2 = z, acc3 = z;

#define ISSUE_A(g0) \
    GLOAD4(a0, src, vbase + (g0 + 0) * 4096u); \
    GLOAD4(a1, src, vbase + (g0 + 1) * 4096u); \
    GLOAD4(a2, src, vbase + (g0 + 2) * 4096u); \
    GLOAD4(a3, src, vbase + (g0 + 3) * 4096u); \
    GLOAD4(a4, src, vbase + (g0 + 4) * 4096u); \
    GLOAD4(a5, src, vbase + (g0 + 5) * 4096u); \
    GLOAD4(a6, src, vbase + (g0 + 6) * 4096u); \
    GLOAD4(a7, src, vbase + (g0 + 7) * 4096u)
#define ISSUE_B(g0) \
    GLOAD4(b0, src, vbase + (g0 + 0) * 4096u); \
    GLOAD4(b1, src, vbase + (g0 + 1) * 4096u); \
    GLOAD4(b2, src, vbase + (g0 + 2) * 4096u); \
    GLOAD4(b3, src, vbase + (g0 + 3) * 4096u); \
    GLOAD4(b4, src, vbase + (g0 + 4) * 4096u); \
    GLOAD4(b5, src, vbase + (g0 + 5) * 4096u); \
    GLOAD4(b6, src, vbase + (g0 + 6) * 4096u); \
    GLOAD4(b7, src, vbase + (g0 + 7) * 4096u)
#define CONSUME_A() \
    ADD4(acc0, a0); ADD4(acc1, a1); ADD4(acc2, a2); ADD4(acc3, a3); \
    ADD4(acc0, a4); ADD4(acc1, a5); ADD4(acc2, a6); ADD4(acc3, a7)
#define CONSUME_B() \
    ADD4(acc0, b0); ADD4(acc1, b1); ADD4(acc2, b2); ADD4(acc3, b3); \
    ADD4(acc0, b4); ADD4(acc1, b5); ADD4(acc2, b6); ADD4(acc3, b7)

    ISSUE_A(0u);                 // j = 0..7     outstanding: 8
    ISSUE_B(8u);                 // j = 8..15    outstanding: 16
    WAITV(8); SBAR();            // A done
    CONSUME_A();
    ISSUE_A(16u);                // j = 16..23   outstanding: 16
    WAITV(8); SBAR();            // B done
    CONSUME_B();
    ISSUE_B(24u);                // j = 24..31   outstanding: 16
    WAITV(8); SBAR();            // A done
    CONSUME_A();
    WAITV(0); SBAR();            // B done
    CONSUME_B();

    ADD4(acc0, acc1);
    ADD4(acc2, acc3);
    ADD4(acc0, acc2);
    red[t] = acc0;               // bin: cls=(t>>5)&3 (w%4), c4=t&31
    __syncthreads();

    if (t < 128) {               // t and t+128 share the same bin
        float4 s = red[t];
        const float4 p = red[t + 128];
        ADD4(s, p);
        // permuted position: pi = nh*256 + g*2 + half  (nh=(bb>>1)&3, g=bb>>3, half=bb&1)
        const int pi = ((bb >> 1) & 3) * 256 + (bb >> 3) * 2 + (bb & 1);
        p4[(isv ? 131072 : 0) + pi * 128 + t] = s;   // slot t = cls*32 + c4
    }
}

// ---------------- kernel 1 phase 2 (fused with prep): partials -> k2/v2 ----
// 32 blocks x 256 thr. b: src=b>>4, nh=(b>>2)&3, n0=b&3; n = nh*4+n0.
// Thread (w0=t>>5, c4=t&31) sums 32 partials p4[src][nh*256 + w0*32+jj][n0*32+c4].
// LDS-combine the 8 w0 copies -> 32 lanes hold the (n, c4) sums; mean /16384;
// k-side: per-head L2 norm via 8-lane DPP reduce, fold exp(min(ls,log100)),
// write k2[h][n][dq]; v-side: write mean to v2.
__global__ __launch_bounds__(256) void k_finish(const float4* __restrict__ p4,
                                                const float* __restrict__ logit_scale,
                                                float4* __restrict__ k2f4,
                                                float4* __restrict__ v2f4) {
    __shared__ float4 lsum[256];
    const int b = blockIdx.x;
    const int srcv = b >> 4;
    const int nh = (b >> 2) & 3;
    const int n0 = b & 3;
    const int n = nh * 4 + n0;
    const int t = threadIdx.x;
    const int w0 = t >> 5;
    const int c4 = t & 31;

    const float4* base = p4 + srcv * 131072 + (nh * 256 + w0 * 32) * 128 + n0 * 32 + c4;
    float4 s = make_float4(0.f, 0.f, 0.f, 0.f);
#pragma unroll
    for (int jj = 0; jj < 32; ++jj) {
        const float4 x = base[jj * 128];
        ADD4(s, x);
    }
    lsum[t] = s;
    __syncthreads();

    if (t < 32) {
        float4 m = lsum[t];
#pragma unroll
        for (int w = 1; w < 8; ++w) {
            const float4 x = lsum[w * 32 + t];
            ADD4(m, x);
        }
        const float inv = 1.0f / 16384.0f;
        m.x *= inv; m.y *= inv; m.z *= inv; m.w *= inv;

        const int h = t >> 3;        // head of this c4-quad
        const int dq = t & 7;        // d-quad within head
        if (srcv == 0) {
            float ss = m.x * m.x + m.y * m.y + m.z * m.z + m.w * m.w;
            ss += dppf<DPP_XOR1>(ss);
            ss += dppf<DPP_XOR2>(ss);
            ss += dppf<DPP_MIR8>(ss);   // per-head sum over its 8 lanes
            const float sc = __expf(fminf(logit_scale[h], 4.6051702f)); // log(1/0.01)
            const float f = sc / fmaxf(sqrtf(ss), 1e-12f);
            k2f4[h * 128 + n * 8 + dq] = make_float4(m.x * f, m.y * f, m.z * f, m.w * f);
        } else {
            v2f4[h * 128 + n * 8 + dq] = m;
        }
    }
}

// ---------------- fallback (ws too small): atomic version + prep ----------------
__global__ __launch_bounds__(256) void k_reduce_atomic(const float4* __restrict__ k4,
                                                       const float4* __restrict__ v4,
                                                       float* __restrict__ ksum,
                                                       float* __restrict__ vsum) {
    __shared__ float4 stage[2048];
    __shared__ float4 redE[256];
    __shared__ float4 redO[256];
    const int t = threadIdx.x;
    const int b = blockIdx.x;
    const bool isv = (b >= 1024);
    const int bb = b & 1023;
    const float4* __restrict__ src = isv ? v4 : k4;
    float* __restrict__ dst = isv ? vsum : ksum;

    const int wv = t >> 6;
    const int ln = t & 63;
    const long gstart = (long)bb * 8192 + wv * 2048;
    const float4* gsrc = src + gstart + ln;
    char* lbase = (char*)stage + wv * 8192;

#pragma unroll
    for (int j = 0; j < 4; ++j)
        gload_lds16(gsrc + j * 64, lbase + j * 1024);

    float4 z = make_float4(0.f, 0.f, 0.f, 0.f);
    float4 accE = z, accO = z;

#pragma unroll
    for (int c = 0; c < 8; ++c) {
        if (c < 7) {
            const int p1 = (c + 1) & 1;
#pragma unroll
            for (int j = 0; j < 4; ++j)
                gload_lds16(gsrc + (c + 1) * 256 + j * 64,
                            lbase + p1 * 4096 + j * 1024);
            asm volatile("s_waitcnt vmcnt(4)" ::: "memory");
        } else {
            asm volatile("s_waitcnt vmcnt(0)" ::: "memory");
        }
        __builtin_amdgcn_sched_barrier(0);
        const int p = c & 1;
        const float4* lf = (const float4*)(lbase + p * 4096) + ln;
        const float4 x0 = lf[0];
        const float4 x1 = lf[64];
        const float4 x2 = lf[128];
        const float4 x3 = lf[192];
        ADD4(accE, x0); ADD4(accO, x1); ADD4(accE, x2); ADD4(accO, x3);
    }

    redE[wv * 64 + ln] = accE;
    redO[wv * 64 + ln] = accO;
    __syncthreads();

    if (t < 128) {
        const int n0 = t >> 5;
        const int c4 = t & 31;
        const float4* arr = (n0 < 2) ? redE : redO;
        const int base = (n0 & 1) * 32 + c4;
        float4 s = arr[base];
        const float4 s1 = arr[base + 64];
        const float4 s2 = arr[base + 128];
        const float4 s3 = arr[base + 192];
        ADD4(s, s1); ADD4(s, s2); ADD4(s, s3);
        const int n = ((bb >> 1) & 3) * 4 + n0;
        const int c = c4 * 4;
        atomicAdd(&dst[n * 128 + c + 0], s.x);
        atomicAdd(&dst[n * 128 + c + 1], s.y);
        atomicAdd(&dst[n * 128 + c + 2], s.z);
        atomicAdd(&dst[n * 128 + c + 3], s.w);
    }
}

__global__ __launch_bounds__(256) void k_prep(const float* __restrict__ ksum,
                                              const float* __restrict__ vsum,
                                              const float* __restrict__ logit_scale,
                                              float* __restrict__ k2,
                                              float* __restrict__ v2) {
    __shared__ float mk[2048], mv[2048], fac[64];
    const int t = threadIdx.x;
    const float inv = 1.0f / 16384.0f;
    for (int w = t; w < 2048; w += 256) {
        mk[w] = ksum[w] * inv;
        mv[w] = vsum[w] * inv;
    }
    __syncthreads();
    if (t < 64) {
        const int h = t >> 4, n = t & 15;
        float ss = 0.f;
#pragma unroll
        for (int d = 0; d < 32; ++d) {
            float x = mk[n * 128 + h * 32 + d];
            ss += x * x;
        }
        const float nrm = sqrtf(ss);
        const float sc = __expf(fminf(logit_scale[h], 4.6051702f));
        fac[t] = sc / fmaxf(nrm, 1e-12f);
    }
    __syncthreads();
    for (int w = t; w < 2048; w += 256) {
        const int h = w >> 9;
        const int n = (w & 511) >> 5;
        const int d = w & 31;
        const float f = fac[h * 16 + n];
        k2[w] = mk[n * 128 + h * 32 + d] * f;
        v2[w] = mv[n * 128 + h * 32 + d];
    }
}

// ---------------- kernel 2: per-query attention (at roofline - unchanged) ----
__global__ __launch_bounds__(256, 2) void k_attn(const float4* __restrict__ q4,
                                                 const float2* __restrict__ mask2,
                                                 const float4* __restrict__ k2f4,
                                                 const float4* __restrict__ v2f4,
                                                 float4* __restrict__ out4) {
    const int t = threadIdx.x;
    const int isub = t >> 5;       // 0..7
    const int l5 = t & 31;
    const int h = l5 >> 3;         // head
    const int g = l5 & 7;          // d-quad within head

    float4 kreg[16], vreg[16];
#pragma unroll
    for (int n = 0; n < 16; ++n) {
        kreg[n] = k2f4[h * 128 + n * 8 + g];
        vreg[n] = v2f4[h * 128 + n * 8 + g];
    }

    const bool b2 = (g & 4) != 0;
    const bool b1 = (g & 2) != 0;
    const bool b0 = (g & 1) != 0;

    auto process = [&](const float4 qv, const float2 mw) -> float4 {
        float ss = qv.x * qv.x + qv.y * qv.y + qv.z * qv.z + qv.w * qv.w;
        ss += dppf<DPP_XOR1>(ss);
        ss += dppf<DPP_XOR2>(ss);
        ss += dppf<DPP_MIR8>(ss);
        const float rn = rsqrtf(fmaxf(ss, 1e-24f));
        const float qx = qv.x * rn, qy = qv.y * rn, qz = qv.z * rn, qw = qv.w * rn;

        float part[16];
#pragma unroll
        for (int n = 0; n < 16; ++n)
            part[n] = qx * kreg[n].x + qy * kreg[n].y + qz * kreg[n].z + qw * kreg[n].w;

        float r8[8];
#pragma unroll
        for (int j = 0; j < 8; ++j) {
            const float snd = b2 ? part[j] : part[j + 8];
            const float kp  = b2 ? part[j + 8] : part[j];
            r8[j] = kp + dppf<DPP_MIR8>(snd);
        }
        float r4[4];
#pragma unroll
        for (int j = 0; j < 4; ++j) {
            const float snd = b1 ? r8[j] : r8[j + 4];
            const float kp  = b1 ? r8[j + 4] : r8[j];
            r4[j] = kp + dppf<DPP_XOR2>(snd);
        }
        float s0, s1;
        {
            const float sndA = b0 ? r4[0] : r4[2];
            const float kpA  = b0 ? r4[2] : r4[0];
            s0 = kpA + dppf<DPP_XOR1>(sndA);
            const float sndB = b0 ? r4[1] : r4[3];
            const float kpB  = b0 ? r4[3] : r4[1];
            s1 = kpB + dppf<DPP_XOR1>(sndB);
        }

        const float e0 = __expf(s0 + mw.x);
        const float e1 = __expf(s1 + mw.y);

        float ds = e0 + e1;
        ds += dppf<DPP_XOR1>(ds);
        ds += dppf<DPP_XOR2>(ds);
        ds += dppf<DPP_MIR8>(ds);
        const float rden = 1.0f / ds;

        float pf[16];
        pf[0]  = swzf<(0 << 5) | 0x18>(e0);
        pf[1]  = swzf<(0 << 5) | 0x18>(e1);
        pf[2]  = swzf<(1 << 5) | 0x18>(e0);
        pf[3]  = swzf<(1 << 5) | 0x18>(e1);
        pf[4]  = swzf<(2 << 5) | 0x18>(e0);
        pf[5]  = swzf<(2 << 5) | 0x18>(e1);
        pf[6]  = swzf<(3 << 5) | 0x18>(e0);
        pf[7]  = swzf<(3 << 5) | 0x18>(e1);
        pf[8]  = swzf<(4 << 5) | 0x18>(e0);
        pf[9]  = swzf<(4 << 5) | 0x18>(e1);
        pf[10] = swzf<(5 << 5) | 0x18>(e0);
        pf[11] = swzf<(5 << 5) | 0x18>(e1);
        pf[12] = swzf<(6 << 5) | 0x18>(e0);
        pf[13] = swzf<(6 << 5) | 0x18>(e1);
        pf[14] = swzf<(7 << 5) | 0x18>(e0);
        pf[15] = swzf<(7 << 5) | 0x18>(e1);

        float ox = 0.f, oy = 0.f, oz = 0.f, ow = 0.f;
#pragma unroll
        for (int n = 0; n < 16; ++n) {
            ox += pf[n] * vreg[n].x;
            oy += pf[n] * vreg[n].y;
            oz += pf[n] * vreg[n].z;
            ow += pf[n] * vreg[n].w;
        }
        return make_float4(ox * rden, oy * rden, oz * rden, ow * rden);
    };

    int i = blockIdx.x * 128 + isub;   // queries i and i+8 per iter, stride 16
    float4 qA = q4[i * 32 + h * 8 + g];
    float4 qB = q4[(i + 8) * 32 + h * 8 + g];
    float2 mA = mask2[i * 8 + g];
    float2 mB = mask2[(i + 8) * 8 + g];

#pragma unroll 1
    for (int iter = 0; iter < 8; ++iter) {
        const int ip = (iter < 7) ? (i + 16) : i;   // branchless prefetch (clamped)
        const float4 qA_n = q4[ip * 32 + h * 8 + g];
        const float4 qB_n = q4[(ip + 8) * 32 + h * 8 + g];
        const float2 mA_n = mask2[ip * 8 + g];
        const float2 mB_n = mask2[(ip + 8) * 8 + g];

        const float4 oA = process(qA, mA);
        const float4 oB = process(qB, mB);
        out4[i * 32 + h * 8 + g] = oA;
        out4[(i + 8) * 32 + h * 8 + g] = oB;

        i += 16;
        qA = qA_n; qB = qB_n; mA = mA_n; mB = mB_n;
    }
}

extern "C" void kernel_launch(void* const* d_in, const int* in_sizes, int n_in,
                              void* d_out, int out_size, void* d_ws, size_t ws_size,
                              hipStream_t stream) {
    (void)in_sizes; (void)n_in; (void)out_size;
    const float* q = (const float*)d_in[0];
    const float* k = (const float*)d_in[1];
    const float* v = (const float*)d_in[2];
    const float* mask = (const float*)d_in[5];
    const float* ls = (const float*)d_in[6];

    float* ws = (float*)d_ws;
    float* ksum = ws;
    float* vsum = ws + 2048;
    float* k2 = ws + 4096;
    float* v2 = ws + 6144;
    float* part = ws + 8192;   // 262144 float4 = 4MB

    const size_t needed = (size_t)8192 * 4 + (size_t)262144 * 16;
    if (ws_size >= needed) {
        // two-phase, atomic-free path with fused finish
        k_reduce_p1<<<2048, 256, 0, stream>>>((const float4*)k, (const float4*)v,
                                              (float4*)part);
        k_finish<<<32, 256, 0, stream>>>((const float4*)part, ls,
                                         (float4*)k2, (float4*)v2);
    } else {
        hipMemsetAsync(ws, 0, 4096 * sizeof(float), stream);
        k_reduce_atomic<<<2048, 256, 0, stream>>>((const float4*)k, (const float4*)v,
                                                  ksum, vsum);
        k_prep<<<1, 256, 0, stream>>>(ksum, vsum, ls, k2, v2);
    }
    k_attn<<<2048, 256, 0, stream>>>((const float4*)q, (const float2*)mask,
                                     (const float4*)k2, (const float4*)v2,
                                     (float4*)d_out);
}

// Round 7
// 132.996 us; speedup vs baseline: 1.1606x; 1.0137x over previous
//
#include <hip/hip_runtime.h>

// Problem constants: Q=262144, L=512*512, C=128, window 4x4 -> N=16, 4 heads x 32d. B=1.
// ws layout (floats): [0,2048) ksum, [2048,4096) vsum, [4096,6144) k2[h][n][d],
//                     [6144,8192) v2[h][n][d], [8192,8192+262144) partials (1MB)

// ---------------- DPP / swizzle helpers ----------------
template <int CTRL>
__device__ __forceinline__ float dppf(float x) {
    return __int_as_float(
        __builtin_amdgcn_update_dpp(0, __float_as_int(x), CTRL, 0xF, 0xF, true));
}
#define DPP_XOR1 0xB1
#define DPP_XOR2 0x4E
#define DPP_MIR8 0x141

template <int IMM>
__device__ __forceinline__ float swzf(float x) {
    return __int_as_float(__builtin_amdgcn_ds_swizzle(__float_as_int(x), IMM));
}

#define ADD4(A, B) { A.x += B.x; A.y += B.y; A.z += B.z; A.w += B.w; }

#define GLOAD4(dst, base, vo) \
    asm volatile("global_load_dwordx4 %0, %1, %2" \
                 : "=v"(dst) : "v"(vo), "s"(base) : "memory")
#define WAITV(n) asm volatile("s_waitcnt vmcnt(" #n ")" ::: "memory")
#define SBAR() __builtin_amdgcn_sched_barrier(0)

__device__ __forceinline__ void gload_lds16(const float4* g, void* l) {
    __builtin_amdgcn_global_load_lds(
        (const __attribute__((address_space(1))) unsigned int*)(const void*)g,
        (__attribute__((address_space(3))) unsigned int*)l, 16, 0, 0);
}

// ---------------- kernel 1 phase 1: strided mean reduction of k, v ----------------
// v7: persistent blocks, never-draining pipeline. R1-R6 falsified read-mechanism
// theories (compiler pipeline / global_load_lds DMA / forced 16-deep asm all =
// 95us, even L3-resident). Common factor: 2048 short blocks, each 32 loads then
// full drain (vmcnt->0, sync, endpgm) -> block ramp/drain dominates.
// Now: 512 blocks x 4 tiles each, tiles strided 256 (rows = bb/2 mod 4 const ->
// bins constant -> accumulators persist across tiles). A/B ping-pong keeps 16
// dwordx4 outstanding across ALL 128 loads/thread; vmcnt hits 0 only at the end.
__global__ __launch_bounds__(256, 1) void k_reduce_p1(const float4* __restrict__ k4,
                                                      const float4* __restrict__ v4,
                                                      float4* __restrict__ p4) {
    __shared__ float4 red[256];
    const int t = threadIdx.x;
    const int b = blockIdx.x;          // 0..511
    const bool isv = (b >= 256);
    const int bb = b & 255;
    const float4* __restrict__ src = (isv ? v4 : k4) + (long)bb * 8192;
    const unsigned vbase = (unsigned)t * 16u;

    float4 a0, a1, a2, a3, a4, a5, a6, a7;
    float4 b0, b1, b2, b3, b4, b5, b6, b7;
    float4 z = make_float4(0.f, 0.f, 0.f, 0.f);
    float4 acc0 = z, acc1 = z, acc2 = z, acc3 = z;

    // round r (0..15): tile tl=r>>2 (byte stride 32MB), group (r&3) of 8 loads 4KB apart
#define OFF(r, i) (vbase + (unsigned)(((r) >> 2) * 33554432u + (unsigned)((((r) & 3) * 8 + (i)) * 4096u)))
#define ISSUE(G, r) \
    GLOAD4(G##0, src, OFF(r, 0)); GLOAD4(G##1, src, OFF(r, 1)); \
    GLOAD4(G##2, src, OFF(r, 2)); GLOAD4(G##3, src, OFF(r, 3)); \
    GLOAD4(G##4, src, OFF(r, 4)); GLOAD4(G##5, src, OFF(r, 5)); \
    GLOAD4(G##6, src, OFF(r, 6)); GLOAD4(G##7, src, OFF(r, 7))
#define CONSUME_A() \
    ADD4(acc0, a0); ADD4(acc1, a1); ADD4(acc2, a2); ADD4(acc3, a3); \
    ADD4(acc0, a4); ADD4(acc1, a5); ADD4(acc2, a6); ADD4(acc3, a7)
#define CONSUME_B() \
    ADD4(acc0, b0); ADD4(acc1, b1); ADD4(acc2, b2); ADD4(acc3, b3); \
    ADD4(acc0, b4); ADD4(acc1, b5); ADD4(acc2, b6); ADD4(acc3, b7)

    ISSUE(a, 0);  ISSUE(b, 1);                      // outstanding: 16
    WAITV(8); SBAR(); CONSUME_A(); ISSUE(a, 2);
    WAITV(8); SBAR(); CONSUME_B(); ISSUE(b, 3);
    WAITV(8); SBAR(); CONSUME_A(); ISSUE(a, 4);
    WAITV(8); SBAR(); CONSUME_B(); ISSUE(b, 5);
    WAITV(8); SBAR(); CONSUME_A(); ISSUE(a, 6);
    WAITV(8); SBAR(); CONSUME_B(); ISSUE(b, 7);
    WAITV(8); SBAR(); CONSUME_A(); ISSUE(a, 8);
    WAITV(8); SBAR(); CONSUME_B(); ISSUE(b, 9);
    WAITV(8); SBAR(); CONSUME_A(); ISSUE(a, 10);
    WAITV(8); SBAR(); CONSUME_B(); ISSUE(b, 11);
    WAITV(8); SBAR(); CONSUME_A(); ISSUE(a, 12);
    WAITV(8); SBAR(); CONSUME_B(); ISSUE(b, 13);
    WAITV(8); SBAR(); CONSUME_A(); ISSUE(a, 14);
    WAITV(8); SBAR(); CONSUME_B(); ISSUE(b, 15);
    WAITV(8); SBAR(); CONSUME_A();                  // round 14
    WAITV(0); SBAR(); CONSUME_B();                  // round 15

    ADD4(acc0, acc1);
    ADD4(acc2, acc3);
    ADD4(acc0, acc2);
    red[t] = acc0;               // bin: cls=(t>>5)&3 (col%4), c4=t&31
    __syncthreads();

    if (t < 128) {               // t and t+128 share (cls, c4)
        float4 s = red[t];
        const float4 p = red[t + 128];
        ADD4(s, p);
        // pi groups same-nh blocks contiguously: nh=(bb>>1)&3, g=bb>>3, half=bb&1
        const int pi = ((bb >> 1) & 3) * 64 + (bb >> 3) * 2 + (bb & 1);
        p4[(isv ? 32768 : 0) + pi * 128 + t] = s;   // slot t = cls*32 + c4
    }
}

// ---------------- kernel 1 phase 2 (fused prep): partials -> k2/v2 ----------------
// 32 blocks x 256 thr. b: srcv=b>>4, nh=(b>>2)&3, cls=b&3; n = nh*4+cls.
// 64 partials per bin: pi = nh*64 + w0*8 + jj. LDS-combine 8 w0 copies; mean;
// k-side per-head L2 norm (8-lane DPP) + exp(min(ls,log100)) fold; write k2/v2.
__global__ __launch_bounds__(256) void k_finish(const float4* __restrict__ p4,
                                                const float* __restrict__ logit_scale,
                                                float4* __restrict__ k2f4,
                                                float4* __restrict__ v2f4) {
    __shared__ float4 lsum[256];
    const int b = blockIdx.x;
    const int srcv = b >> 4;
    const int nh = (b >> 2) & 3;
    const int cls = b & 3;
    const int n = nh * 4 + cls;
    const int t = threadIdx.x;
    const int w0 = t >> 5;
    const int c4 = t & 31;

    const float4* base = p4 + srcv * 32768 + (nh * 64 + w0 * 8) * 128 + cls * 32 + c4;
    float4 s = make_float4(0.f, 0.f, 0.f, 0.f);
#pragma unroll
    for (int jj = 0; jj < 8; ++jj) {
        const float4 x = base[jj * 128];
        ADD4(s, x);
    }
    lsum[t] = s;
    __syncthreads();

    if (t < 32) {
        float4 m = lsum[t];
#pragma unroll
        for (int w = 1; w < 8; ++w) {
            const float4 x = lsum[w * 32 + t];
            ADD4(m, x);
        }
        const float inv = 1.0f / 16384.0f;
        m.x *= inv; m.y *= inv; m.z *= inv; m.w *= inv;

        const int h = t >> 3;        // head of this c4-quad
        const int dq = t & 7;        // d-quad within head
        if (srcv == 0) {
            float ss = m.x * m.x + m.y * m.y + m.z * m.z + m.w * m.w;
            ss += dppf<DPP_XOR1>(ss);
            ss += dppf<DPP_XOR2>(ss);
            ss += dppf<DPP_MIR8>(ss);   // per-head sum over its 8 lanes
            const float sc = __expf(fminf(logit_scale[h], 4.6051702f)); // log(1/0.01)
            const float f = sc / fmaxf(sqrtf(ss), 1e-12f);
            k2f4[h * 128 + n * 8 + dq] = make_float4(m.x * f, m.y * f, m.z * f, m.w * f);
        } else {
            v2f4[h * 128 + n * 8 + dq] = m;
        }
    }
}

// ---------------- fallback (ws too small): atomic version + prep ----------------
__global__ __launch_bounds__(256) void k_reduce_atomic(const float4* __restrict__ k4,
                                                       const float4* __restrict__ v4,
                                                       float* __restrict__ ksum,
                                                       float* __restrict__ vsum) {
    __shared__ float4 stage[2048];
    __shared__ float4 redE[256];
    __shared__ float4 redO[256];
    const int t = threadIdx.x;
    const int b = blockIdx.x;
    const bool isv = (b >= 1024);
    const int bb = b & 1023;
    const float4* __restrict__ src = isv ? v4 : k4;
    float* __restrict__ dst = isv ? vsum : ksum;

    const int wv = t >> 6;
    const int ln = t & 63;
    const long gstart = (long)bb * 8192 + wv * 2048;
    const float4* gsrc = src + gstart + ln;
    char* lbase = (char*)stage + wv * 8192;

#pragma unroll
    for (int j = 0; j < 4; ++j)
        gload_lds16(gsrc + j * 64, lbase + j * 1024);

    float4 z = make_float4(0.f, 0.f, 0.f, 0.f);
    float4 accE = z, accO = z;

#pragma unroll
    for (int c = 0; c < 8; ++c) {
        if (c < 7) {
            const int p1 = (c + 1) & 1;
#pragma unroll
            for (int j = 0; j < 4; ++j)
                gload_lds16(gsrc + (c + 1) * 256 + j * 64,
                            lbase + p1 * 4096 + j * 1024);
            asm volatile("s_waitcnt vmcnt(4)" ::: "memory");
        } else {
            asm volatile("s_waitcnt vmcnt(0)" ::: "memory");
        }
        __builtin_amdgcn_sched_barrier(0);
        const int p = c & 1;
        const float4* lf = (const float4*)(lbase + p * 4096) + ln;
        const float4 x0 = lf[0];
        const float4 x1 = lf[64];
        const float4 x2 = lf[128];
        const float4 x3 = lf[192];
        ADD4(accE, x0); ADD4(accO, x1); ADD4(accE, x2); ADD4(accO, x3);
    }

    redE[wv * 64 + ln] = accE;
    redO[wv * 64 + ln] = accO;
    __syncthreads();

    if (t < 128) {
        const int n0 = t >> 5;
        const int c4 = t & 31;
        const float4* arr = (n0 < 2) ? redE : redO;
        const int base = (n0 & 1) * 32 + c4;
        float4 s = arr[base];
        const float4 s1 = arr[base + 64];
        const float4 s2 = arr[base + 128];
        const float4 s3 = arr[base + 192];
        ADD4(s, s1); ADD4(s, s2); ADD4(s, s3);
        const int n = ((bb >> 1) & 3) * 4 + n0;
        const int c = c4 * 4;
        atomicAdd(&dst[n * 128 + c + 0], s.x);
        atomicAdd(&dst[n * 128 + c + 1], s.y);
        atomicAdd(&dst[n * 128 + c + 2], s.z);
        atomicAdd(&dst[n * 128 + c + 3], s.w);
    }
}

__global__ __launch_bounds__(256) void k_prep(const float* __restrict__ ksum,
                                              const float* __restrict__ vsum,
                                              const float* __restrict__ logit_scale,
                                              float* __restrict__ k2,
                                              float* __restrict__ v2) {
    __shared__ float mk[2048], mv[2048], fac[64];
    const int t = threadIdx.x;
    const float inv = 1.0f / 16384.0f;
    for (int w = t; w < 2048; w += 256) {
        mk[w] = ksum[w] * inv;
        mv[w] = vsum[w] * inv;
    }
    __syncthreads();
    if (t < 64) {
        const int h = t >> 4, n = t & 15;
        float ss = 0.f;
#pragma unroll
        for (int d = 0; d < 32; ++d) {
            float x = mk[n * 128 + h * 32 + d];
            ss += x * x;
        }
        const float nrm = sqrtf(ss);
        const float sc = __expf(fminf(logit_scale[h], 4.6051702f));
        fac[t] = sc / fmaxf(nrm, 1e-12f);
    }
    __syncthreads();
    for (int w = t; w < 2048; w += 256) {
        const int h = w >> 9;
        const int n = (w & 511) >> 5;
        const int d = w & 31;
        const float f = fac[h * 16 + n];
        k2[w] = mk[n * 128 + h * 32 + d] * f;
        v2[w] = mv[n * 128 + h * 32 + d];
    }
}

// ---------------- kernel 2: per-query attention (at roofline - unchanged) ----
__global__ __launch_bounds__(256, 2) void k_attn(const float4* __restrict__ q4,
                                                 const float2* __restrict__ mask2,
                                                 const float4* __restrict__ k2f4,
                                                 const float4* __restrict__ v2f4,
                                                 float4* __restrict__ out4) {
    const int t = threadIdx.x;
    const int isub = t >> 5;       // 0..7
    const int l5 = t & 31;
    const int h = l5 >> 3;         // head
    const int g = l5 & 7;          // d-quad within head

    float4 kreg[16], vreg[16];
#pragma unroll
    for (int n = 0; n < 16; ++n) {
        kreg[n] = k2f4[h * 128 + n * 8 + g];
        vreg[n] = v2f4[h * 128 + n * 8 + g];
    }

    const bool b2 = (g & 4) != 0;
    const bool b1 = (g & 2) != 0;
    const bool b0 = (g & 1) != 0;

    auto process = [&](const float4 qv, const float2 mw) -> float4 {
        float ss = qv.x * qv.x + qv.y * qv.y + qv.z * qv.z + qv.w * qv.w;
        ss += dppf<DPP_XOR1>(ss);
        ss += dppf<DPP_XOR2>(ss);
        ss += dppf<DPP_MIR8>(ss);
        const float rn = rsqrtf(fmaxf(ss, 1e-24f));
        const float qx = qv.x * rn, qy = qv.y * rn, qz = qv.z * rn, qw = qv.w * rn;

        float part[16];
#pragma unroll
        for (int n = 0; n < 16; ++n)
            part[n] = qx * kreg[n].x + qy * kreg[n].y + qz * kreg[n].z + qw * kreg[n].w;

        float r8[8];
#pragma unroll
        for (int j = 0; j < 8; ++j) {
            const float snd = b2 ? part[j] : part[j + 8];
            const float kp  = b2 ? part[j + 8] : part[j];
            r8[j] = kp + dppf<DPP_MIR8>(snd);
        }
        float r4[4];
#pragma unroll
        for (int j = 0; j < 4; ++j) {
            const float snd = b1 ? r8[j] : r8[j + 4];
            const float kp  = b1 ? r8[j + 4] : r8[j];
            r4[j] = kp + dppf<DPP_XOR2>(snd);
        }
        float s0, s1;
        {
            const float sndA = b0 ? r4[0] : r4[2];
            const float kpA  = b0 ? r4[2] : r4[0];
            s0 = kpA + dppf<DPP_XOR1>(sndA);
            const float sndB = b0 ? r4[1] : r4[3];
            const float kpB  = b0 ? r4[3] : r4[1];
            s1 = kpB + dppf<DPP_XOR1>(sndB);
        }

        const float e0 = __expf(s0 + mw.x);
        const float e1 = __expf(s1 + mw.y);

        float ds = e0 + e1;
        ds += dppf<DPP_XOR1>(ds);
        ds += dppf<DPP_XOR2>(ds);
        ds += dppf<DPP_MIR8>(ds);
        const float rden = 1.0f / ds;

        float pf[16];
        pf[0]  = swzf<(0 << 5) | 0x18>(e0);
        pf[1]  = swzf<(0 << 5) | 0x18>(e1);
        pf[2]  = swzf<(1 << 5) | 0x18>(e0);
        pf[3]  = swzf<(1 << 5) | 0x18>(e1);
        pf[4]  = swzf<(2 << 5) | 0x18>(e0);
        pf[5]  = swzf<(2 << 5) | 0x18>(e1);
        pf[6]  = swzf<(3 << 5) | 0x18>(e0);
        pf[7]  = swzf<(3 << 5) | 0x18>(e1);
        pf[8]  = swzf<(4 << 5) | 0x18>(e0);
        pf[9]  = swzf<(4 << 5) | 0x18>(e1);
        pf[10] = swzf<(5 << 5) | 0x18>(e0);
        pf[11] = swzf<(5 << 5) | 0x18>(e1);
        pf[12] = swzf<(6 << 5) | 0x18>(e0);
        pf[13] = swzf<(6 << 5) | 0x18>(e1);
        pf[14] = swzf<(7 << 5) | 0x18>(e0);
        pf[15] = swzf<(7 << 5) | 0x18>(e1);

        float ox = 0.f, oy = 0.f, oz = 0.f, ow = 0.f;
#pragma unroll
        for (int n = 0; n < 16; ++n) {
            ox += pf[n] * vreg[n].x;
            oy += pf[n] * vreg[n].y;
            oz += pf[n] * vreg[n].z;
            ow += pf[n] * vreg[n].w;
        }
        return make_float4(ox * rden, oy * rden, oz * rden, ow * rden);
    };

    int i = blockIdx.x * 128 + isub;   // queries i and i+8 per iter, stride 16
    float4 qA = q4[i * 32 + h * 8 + g];
    float4 qB = q4[(i + 8) * 32 + h * 8 + g];
    float2 mA = mask2[i * 8 + g];
    float2 mB = mask2[(i + 8) * 8 + g];

#pragma unroll 1
    for (int iter = 0; iter < 8; ++iter) {
        const int ip = (iter < 7) ? (i + 16) : i;   // branchless prefetch (clamped)
        const float4 qA_n = q4[ip * 32 + h * 8 + g];
        const float4 qB_n = q4[(ip + 8) * 32 + h * 8 + g];
        const float2 mA_n = mask2[ip * 8 + g];
        const float2 mB_n = mask2[(ip + 8) * 8 + g];

        const float4 oA = process(qA, mA);
        const float4 oB = process(qB, mB);
        out4[i * 32 + h * 8 + g] = oA;
        out4[(i + 8) * 32 + h * 8 + g] = oB;

        i += 16;
        qA = qA_n; qB = qB_n; mA = mA_n; mB = mB_n;
    }
}

extern "C" void kernel_launch(void* const* d_in, const int* in_sizes, int n_in,
                              void* d_out, int out_size, void* d_ws, size_t ws_size,
                              hipStream_t stream) {
    (void)in_sizes; (void)n_in; (void)out_size;
    const float* q = (const float*)d_in[0];
    const float* k = (const float*)d_in[1];
    const float* v = (const float*)d_in[2];
    const float* mask = (const float*)d_in[5];
    const float* ls = (const float*)d_in[6];

    float* ws = (float*)d_ws;
    float* ksum = ws;
    float* vsum = ws + 2048;
    float* k2 = ws + 4096;
    float* v2 = ws + 6144;
    float* part = ws + 8192;   // 65536 float4 = 1MB

    const size_t needed = (size_t)8192 * 4 + (size_t)65536 * 16;
    if (ws_size >= needed) {
        k_reduce_p1<<<512, 256, 0, stream>>>((const float4*)k, (const float4*)v,
                                             (float4*)part);
        k_finish<<<32, 256, 0, stream>>>((const float4*)part, ls,
                                         (float4*)k2, (float4*)v2);
    } else {
        hipMemsetAsync(ws, 0, 4096 * sizeof(float), stream);
        k_reduce_atomic<<<2048, 256, 0, stream>>>((const float4*)k, (const float4*)v,
                                                  ksum, vsum);
        k_prep<<<1, 256, 0, stream>>>(ksum, vsum, ls, k2, v2);
    }
    k_attn<<<2048, 256, 0, stream>>>((const float4*)q, (const float2*)mask,
                                     (const float4*)k2, (const float4*)v2,
                                     (float4*)d_out);
}

// Round 8
// 131.072 us; speedup vs baseline: 1.1777x; 1.0147x over previous
//
#include <hip/hip_runtime.h>

// Problem constants: Q=262144, L=512*512, C=128, window 4x4 -> N=16, 4 heads x 32d. B=1.
// ws layout (floats): [0,2048) ksum, [2048,4096) vsum, [4096,6144) k2[h][n][d],
//                     [6144,8192) v2[h][n][d], [8192,8192+524288) partials (2MB)

// ---------------- DPP / swizzle helpers ----------------
template <int CTRL>
__device__ __forceinline__ float dppf(float x) {
    return __int_as_float(
        __builtin_amdgcn_update_dpp(0, __float_as_int(x), CTRL, 0xF, 0xF, true));
}
#define DPP_XOR1 0xB1
#define DPP_XOR2 0x4E
#define DPP_MIR8 0x141

template <int IMM>
__device__ __forceinline__ float swzf(float x) {
    return __int_as_float(__builtin_amdgcn_ds_swizzle(__float_as_int(x), IMM));
}

#define ADD4(A, B) { A.x += B.x; A.y += B.y; A.z += B.z; A.w += B.w; }

#define GLOAD4(dst, base, vo) \
    asm volatile("global_load_dwordx4 %0, %1, %2" \
                 : "=v"(dst) : "v"(vo), "s"(base) : "memory")
#define WAITV(n) asm volatile("s_waitcnt vmcnt(" #n ")" ::: "memory")
#define SBAR() __builtin_amdgcn_sched_barrier(0)

__device__ __forceinline__ void gload_lds16(const float4* g, void* l) {
    __builtin_amdgcn_global_load_lds(
        (const __attribute__((address_space(1))) unsigned int*)(const void*)g,
        (__attribute__((address_space(3))) unsigned int*)l, 16, 0, 0);
}

// ---------------- kernel 1 phase 1: grid-stride mean reduction of k, v ----------
// v8: GRID-STRIDE address pattern. R1-R7 falsified read-mechanism (compiler /
// DMA / forced asm), concurrency, atomics, and block-lifetime theories: all
// ~95us, even fully L3-resident (R7 replays: FETCH=1MB, same 97us). The one
// constant was per-block CONTIGUOUS ALIGNED TILES marching in lockstep ->
// persistent HBM-channel / L3-slice hotspotting (interleave-phase aligned
// across all blocks). Fast kernels (m13 copy 6.3 TB/s, k_attn ~7 TB/s) are
// grid-strided. Here: f4 index f = j*131072 + bb*256 + t; at any instant the
// 512 blocks/array cover 512 distinct 4KB stripes spanning 2MB -> all
// channels/slices uniformly busy. Bin classes remain static: col cls =
// (t>>5)&3 per-thread, row cls = (bb>>6)&3 per-block (no carries). 16
// outstanding asm dwordx4 per wave throughout.
__global__ __launch_bounds__(256, 1) void k_reduce_p1(const float4* __restrict__ k4,
                                                      const float4* __restrict__ v4,
                                                      float4* __restrict__ p4) {
    __shared__ float4 red[256];
    const int t = threadIdx.x;
    const int b = blockIdx.x;          // 0..1023
    const bool isv = (b >= 512);
    const int bb = b & 511;
    const float4* __restrict__ src = isv ? v4 : k4;
    const unsigned vbase = (unsigned)(bb * 256 + t) * 16u;   // byte offset

    float4 a0, a1, a2, a3, a4, a5, a6, a7;
    float4 b0, b1, b2, b3, b4, b5, b6, b7;
    float4 z = make_float4(0.f, 0.f, 0.f, 0.f);
    float4 acc0 = z, acc1 = z, acc2 = z, acc3 = z;

    // load j = g*8+i covers f4 index j*131072 + bb*256 + t  (2MB grid stripe)
#define OFF(g, i) (vbase + (unsigned)(((g) * 8 + (i)) * 2097152u))
#define ISSUE(G, g) \
    GLOAD4(G##0, src, OFF(g, 0)); GLOAD4(G##1, src, OFF(g, 1)); \
    GLOAD4(G##2, src, OFF(g, 2)); GLOAD4(G##3, src, OFF(g, 3)); \
    GLOAD4(G##4, src, OFF(g, 4)); GLOAD4(G##5, src, OFF(g, 5)); \
    GLOAD4(G##6, src, OFF(g, 6)); GLOAD4(G##7, src, OFF(g, 7))
#define CONSUME_A() \
    ADD4(acc0, a0); ADD4(acc1, a1); ADD4(acc2, a2); ADD4(acc3, a3); \
    ADD4(acc0, a4); ADD4(acc1, a5); ADD4(acc2, a6); ADD4(acc3, a7)
#define CONSUME_B() \
    ADD4(acc0, b0); ADD4(acc1, b1); ADD4(acc2, b2); ADD4(acc3, b3); \
    ADD4(acc0, b4); ADD4(acc1, b5); ADD4(acc2, b6); ADD4(acc3, b7)

    ISSUE(a, 0);  ISSUE(b, 1);                      // outstanding: 16
    WAITV(8); SBAR(); CONSUME_A(); ISSUE(a, 2);
    WAITV(8); SBAR(); CONSUME_B(); ISSUE(b, 3);
    WAITV(8); SBAR(); CONSUME_A(); ISSUE(a, 4);
    WAITV(8); SBAR(); CONSUME_B(); ISSUE(b, 5);
    WAITV(8); SBAR(); CONSUME_A(); ISSUE(a, 6);
    WAITV(8); SBAR(); CONSUME_B(); ISSUE(b, 7);
    WAITV(8); SBAR(); CONSUME_A();                  // group 6
    WAITV(0); SBAR(); CONSUME_B();                  // group 7

    ADD4(acc0, acc1);
    ADD4(acc2, acc3);
    ADD4(acc0, acc2);
    red[t] = acc0;               // bin: cc=(t>>5)&3 (col%4), q=t&31 (channel quad)
    __syncthreads();

    if (t < 128) {               // t and t+128 share (cc, q)
        float4 s = red[t];
        const float4 p = red[t + 128];
        ADD4(s, p);
        p4[(isv ? 65536 : 0) + bb * 128 + t] = s;   // slot t = cc*32 + q
    }
}

// ---------------- kernel 1 phase 2 (fused prep): partials -> k2/v2 ----------------
// 32 blocks x 256 thr. b: srcv=b>>4, rc=(b>>2)&3, cc=b&3; n = rc*4+cc.
// Bin (srcv, rc, cc, q) sums partials from the 128 blocks with (bb>>6)&3==rc:
// bb = b1*256 + rc*64 + b0. Thread (w0=t>>5, q=t&31) takes b1 in {0,1},
// b0 in [w0*8, w0*8+8) -> 16 partials; LDS-combine 8 w0 copies; mean /16384;
// k-side per-head L2 norm (8-lane DPP) + exp(min(ls,log100)) fold; write k2/v2.
__global__ __launch_bounds__(256) void k_finish(const float4* __restrict__ p4,
                                                const float* __restrict__ logit_scale,
                                                float4* __restrict__ k2f4,
                                                float4* __restrict__ v2f4) {
    __shared__ float4 lsum[256];
    const int b = blockIdx.x;
    const int srcv = b >> 4;
    const int rc = (b >> 2) & 3;
    const int cc = b & 3;
    const int n = rc * 4 + cc;
    const int t = threadIdx.x;
    const int w0 = t >> 5;
    const int q = t & 31;

    const float4* base = p4 + srcv * 65536 + cc * 32 + q;
    float4 s = make_float4(0.f, 0.f, 0.f, 0.f);
#pragma unroll
    for (int b1 = 0; b1 < 2; ++b1) {
#pragma unroll
        for (int j = 0; j < 8; ++j) {
            const int bb = b1 * 256 + rc * 64 + w0 * 8 + j;
            const float4 x = base[bb * 128];
            ADD4(s, x);
        }
    }
    lsum[t] = s;
    __syncthreads();

    if (t < 32) {
        float4 m = lsum[t];
#pragma unroll
        for (int w = 1; w < 8; ++w) {
            const float4 x = lsum[w * 32 + t];
            ADD4(m, x);
        }
        const float inv = 1.0f / 16384.0f;
        m.x *= inv; m.y *= inv; m.z *= inv; m.w *= inv;

        const int h = t >> 3;        // head of this channel-quad
        const int dq = t & 7;        // d-quad within head
        if (srcv == 0) {
            float ss = m.x * m.x + m.y * m.y + m.z * m.z + m.w * m.w;
            ss += dppf<DPP_XOR1>(ss);
            ss += dppf<DPP_XOR2>(ss);
            ss += dppf<DPP_MIR8>(ss);   // per-head sum over its 8 lanes
            const float sc = __expf(fminf(logit_scale[h], 4.6051702f)); // log(1/0.01)
            const float f = sc / fmaxf(sqrtf(ss), 1e-12f);
            k2f4[h * 128 + n * 8 + dq] = make_float4(m.x * f, m.y * f, m.z * f, m.w * f);
        } else {
            v2f4[h * 128 + n * 8 + dq] = m;
        }
    }
}

// ---------------- fallback (ws too small): atomic version + prep ----------------
__global__ __launch_bounds__(256) void k_reduce_atomic(const float4* __restrict__ k4,
                                                       const float4* __restrict__ v4,
                                                       float* __restrict__ ksum,
                                                       float* __restrict__ vsum) {
    __shared__ float4 stage[2048];
    __shared__ float4 redE[256];
    __shared__ float4 redO[256];
    const int t = threadIdx.x;
    const int b = blockIdx.x;
    const bool isv = (b >= 1024);
    const int bb = b & 1023;
    const float4* __restrict__ src = isv ? v4 : k4;
    float* __restrict__ dst = isv ? vsum : ksum;

    const int wv = t >> 6;
    const int ln = t & 63;
    const long gstart = (long)bb * 8192 + wv * 2048;
    const float4* gsrc = src + gstart + ln;
    char* lbase = (char*)stage + wv * 8192;

#pragma unroll
    for (int j = 0; j < 4; ++j)
        gload_lds16(gsrc + j * 64, lbase + j * 1024);

    float4 z = make_float4(0.f, 0.f, 0.f, 0.f);
    float4 accE = z, accO = z;

#pragma unroll
    for (int c = 0; c < 8; ++c) {
        if (c < 7) {
            const int p1 = (c + 1) & 1;
#pragma unroll
            for (int j = 0; j < 4; ++j)
                gload_lds16(gsrc + (c + 1) * 256 + j * 64,
                            lbase + p1 * 4096 + j * 1024);
            asm volatile("s_waitcnt vmcnt(4)" ::: "memory");
        } else {
            asm volatile("s_waitcnt vmcnt(0)" ::: "memory");
        }
        __builtin_amdgcn_sched_barrier(0);
        const int p = c & 1;
        const float4* lf = (const float4*)(lbase + p * 4096) + ln;
        const float4 x0 = lf[0];
        const float4 x1 = lf[64];
        const float4 x2 = lf[128];
        const float4 x3 = lf[192];
        ADD4(accE, x0); ADD4(accO, x1); ADD4(accE, x2); ADD4(accO, x3);
    }

    redE[wv * 64 + ln] = accE;
    redO[wv * 64 + ln] = accO;
    __syncthreads();

    if (t < 128) {
        const int n0 = t >> 5;
        const int c4 = t & 31;
        const float4* arr = (n0 < 2) ? redE : redO;
        const int base = (n0 & 1) * 32 + c4;
        float4 s = arr[base];
        const float4 s1 = arr[base + 64];
        const float4 s2 = arr[base + 128];
        const float4 s3 = arr[base + 192];
        ADD4(s, s1); ADD4(s, s2); ADD4(s, s3);
        const int n = ((bb >> 1) & 3) * 4 + n0;
        const int c = c4 * 4;
        atomicAdd(&dst[n * 128 + c + 0], s.x);
        atomicAdd(&dst[n * 128 + c + 1], s.y);
        atomicAdd(&dst[n * 128 + c + 2], s.z);
        atomicAdd(&dst[n * 128 + c + 3], s.w);
    }
}

__global__ __launch_bounds__(256) void k_prep(const float* __restrict__ ksum,
                                              const float* __restrict__ vsum,
                                              const float* __restrict__ logit_scale,
                                              float* __restrict__ k2,
                                              float* __restrict__ v2) {
    __shared__ float mk[2048], mv[2048], fac[64];
    const int t = threadIdx.x;
    const float inv = 1.0f / 16384.0f;
    for (int w = t; w < 2048; w += 256) {
        mk[w] = ksum[w] * inv;
        mv[w] = vsum[w] * inv;
    }
    __syncthreads();
    if (t < 64) {
        const int h = t >> 4, n = t & 15;
        float ss = 0.f;
#pragma unroll
        for (int d = 0; d < 32; ++d) {
            float x = mk[n * 128 + h * 32 + d];
            ss += x * x;
        }
        const float nrm = sqrtf(ss);
        const float sc = __expf(fminf(logit_scale[h], 4.6051702f));
        fac[t] = sc / fmaxf(nrm, 1e-12f);
    }
    __syncthreads();
    for (int w = t; w < 2048; w += 256) {
        const int h = w >> 9;
        const int n = (w & 511) >> 5;
        const int d = w & 31;
        const float f = fac[h * 16 + n];
        k2[w] = mk[n * 128 + h * 32 + d] * f;
        v2[w] = mv[n * 128 + h * 32 + d];
    }
}

// ---------------- kernel 2: per-query attention (at roofline - unchanged) ----
__global__ __launch_bounds__(256, 2) void k_attn(const float4* __restrict__ q4,
                                                 const float2* __restrict__ mask2,
                                                 const float4* __restrict__ k2f4,
                                                 const float4* __restrict__ v2f4,
                                                 float4* __restrict__ out4) {
    const int t = threadIdx.x;
    const int isub = t >> 5;       // 0..7
    const int l5 = t & 31;
    const int h = l5 >> 3;         // head
    const int g = l5 & 7;          // d-quad within head

    float4 kreg[16], vreg[16];
#pragma unroll
    for (int n = 0; n < 16; ++n) {
        kreg[n] = k2f4[h * 128 + n * 8 + g];
        vreg[n] = v2f4[h * 128 + n * 8 + g];
    }

    const bool b2 = (g & 4) != 0;
    const bool b1 = (g & 2) != 0;
    const bool b0 = (g & 1) != 0;

    auto process = [&](const float4 qv, const float2 mw) -> float4 {
        float ss = qv.x * qv.x + qv.y * qv.y + qv.z * qv.z + qv.w * qv.w;
        ss += dppf<DPP_XOR1>(ss);
        ss += dppf<DPP_XOR2>(ss);
        ss += dppf<DPP_MIR8>(ss);
        const float rn = rsqrtf(fmaxf(ss, 1e-24f));
        const float qx = qv.x * rn, qy = qv.y * rn, qz = qv.z * rn, qw = qv.w * rn;

        float part[16];
#pragma unroll
        for (int n = 0; n < 16; ++n)
            part[n] = qx * kreg[n].x + qy * kreg[n].y + qz * kreg[n].z + qw * kreg[n].w;

        float r8[8];
#pragma unroll
        for (int j = 0; j < 8; ++j) {
            const float snd = b2 ? part[j] : part[j + 8];
            const float kp  = b2 ? part[j + 8] : part[j];
            r8[j] = kp + dppf<DPP_MIR8>(snd);
        }
        float r4[4];
#pragma unroll
        for (int j = 0; j < 4; ++j) {
            const float snd = b1 ? r8[j] : r8[j + 4];
            const float kp  = b1 ? r8[j + 4] : r8[j];
            r4[j] = kp + dppf<DPP_XOR2>(snd);
        }
        float s0, s1;
        {
            const float sndA = b0 ? r4[0] : r4[2];
            const float kpA  = b0 ? r4[2] : r4[0];
            s0 = kpA + dppf<DPP_XOR1>(sndA);
            const float sndB = b0 ? r4[1] : r4[3];
            const float kpB  = b0 ? r4[3] : r4[1];
            s1 = kpB + dppf<DPP_XOR1>(sndB);
        }

        const float e0 = __expf(s0 + mw.x);
        const float e1 = __expf(s1 + mw.y);

        float ds = e0 + e1;
        ds += dppf<DPP_XOR1>(ds);
        ds += dppf<DPP_XOR2>(ds);
        ds += dppf<DPP_MIR8>(ds);
        const float rden = 1.0f / ds;

        float pf[16];
        pf[0]  = swzf<(0 << 5) | 0x18>(e0);
        pf[1]  = swzf<(0 << 5) | 0x18>(e1);
        pf[2]  = swzf<(1 << 5) | 0x18>(e0);
        pf[3]  = swzf<(1 << 5) | 0x18>(e1);
        pf[4]  = swzf<(2 << 5) | 0x18>(e0);
        pf[5]  = swzf<(2 << 5) | 0x18>(e1);
        pf[6]  = swzf<(3 << 5) | 0x18>(e0);
        pf[7]  = swzf<(3 << 5) | 0x18>(e1);
        pf[8]  = swzf<(4 << 5) | 0x18>(e0);
        pf[9]  = swzf<(4 << 5) | 0x18>(e1);
        pf[10] = swzf<(5 << 5) | 0x18>(e0);
        pf[11] = swzf<(5 << 5) | 0x18>(e1);
        pf[12] = swzf<(6 << 5) | 0x18>(e0);
        pf[13] = swzf<(6 << 5) | 0x18>(e1);
        pf[14] = swzf<(7 << 5) | 0x18>(e0);
        pf[15] = swzf<(7 << 5) | 0x18>(e1);

        float ox = 0.f, oy = 0.f, oz = 0.f, ow = 0.f;
#pragma unroll
        for (int n = 0; n < 16; ++n) {
            ox += pf[n] * vreg[n].x;
            oy += pf[n] * vreg[n].y;
            oz += pf[n] * vreg[n].z;
            ow += pf[n] * vreg[n].w;
        }
        return make_float4(ox * rden, oy * rden, oz * rden, ow * rden);
    };

    int i = blockIdx.x * 128 + isub;   // queries i and i+8 per iter, stride 16
    float4 qA = q4[i * 32 + h * 8 + g];
    float4 qB = q4[(i + 8) * 32 + h * 8 + g];
    float2 mA = mask2[i * 8 + g];
    float2 mB = mask2[(i + 8) * 8 + g];

#pragma unroll 1
    for (int iter = 0; iter < 8; ++iter) {
        const int ip = (iter < 7) ? (i + 16) : i;   // branchless prefetch (clamped)
        const float4 qA_n = q4[ip * 32 + h * 8 + g];
        const float4 qB_n = q4[(ip + 8) * 32 + h * 8 + g];
        const float2 mA_n = mask2[ip * 8 + g];
        const float2 mB_n = mask2[(ip + 8) * 8 + g];

        const float4 oA = process(qA, mA);
        const float4 oB = process(qB, mB);
        out4[i * 32 + h * 8 + g] = oA;
        out4[(i + 8) * 32 + h * 8 + g] = oB;

        i += 16;
        qA = qA_n; qB = qB_n; mA = mA_n; mB = mB_n;
    }
}

extern "C" void kernel_launch(void* const* d_in, const int* in_sizes, int n_in,
                              void* d_out, int out_size, void* d_ws, size_t ws_size,
                              hipStream_t stream) {
    (void)in_sizes; (void)n_in; (void)out_size;
    const float* q = (const float*)d_in[0];
    const float* k = (const float*)d_in[1];
    const float* v = (const float*)d_in[2];
    const float* mask = (const float*)d_in[5];
    const float* ls = (const float*)d_in[6];

    float* ws = (float*)d_ws;
    float* ksum = ws;
    float* vsum = ws + 2048;
    float* k2 = ws + 4096;
    float* v2 = ws + 6144;
    float* part = ws + 8192;   // 131072 float4 = 2MB

    const size_t needed = (size_t)8192 * 4 + (size_t)131072 * 16;
    if (ws_size >= needed) {
        k_reduce_p1<<<1024, 256, 0, stream>>>((const float4*)k, (const float4*)v,
                                              (float4*)part);
        k_finish<<<32, 256, 0, stream>>>((const float4*)part, ls,
                                         (float4*)k2, (float4*)v2);
    } else {
        hipMemsetAsync(ws, 0, 4096 * sizeof(float), stream);
        k_reduce_atomic<<<2048, 256, 0, stream>>>((const float4*)k, (const float4*)v,
                                                  ksum, vsum);
        k_prep<<<1, 256, 0, stream>>>(ksum, vsum, ls, k2, v2);
    }
    k_attn<<<2048, 256, 0, stream>>>((const float4*)q, (const float2*)mask,
                                     (const float4*)k2, (const float4*)v2,
                                     (float4*)d_out);
}

// Round 9
// 119.199 us; speedup vs baseline: 1.2950x; 1.0996x over previous
//
#include <hip/hip_runtime.h>

// Problem constants: Q=262144, L=512*512, C=128, window 4x4 -> N=16, 4 heads x 32d. B=1.
// ws layout (floats): [0,2048) ksum, [2048,4096) vsum, [4096,6144) k2[h][n][d],
//                     [6144,8192) v2[h][n][d], [8192,8192+524288) partials (2MB)

// ---------------- DPP / swizzle helpers ----------------
template <int CTRL>
__device__ __forceinline__ float dppf(float x) {
    return __int_as_float(
        __builtin_amdgcn_update_dpp(0, __float_as_int(x), CTRL, 0xF, 0xF, true));
}
#define DPP_XOR1 0xB1
#define DPP_XOR2 0x4E
#define DPP_MIR8 0x141

template <int IMM>
__device__ __forceinline__ float swzf(float x) {
    return __int_as_float(__builtin_amdgcn_ds_swizzle(__float_as_int(x), IMM));
}

#define ADD4(A, B) { A.x += B.x; A.y += B.y; A.z += B.z; A.w += B.w; }

// v9: NON-TEMPORAL raw loads. 8 rounds showed ~2.8 TB/s read-only regardless of
// mechanism/concurrency/lifetime/address-pattern; FETCH=134MB of 268MB (half L3
// retention). Hypothesis: per-byte L2/L3 allocation (fill) work is the cap ->
// nt (no-allocate) loads may stream at raw HBM read rate, and free the L3 to
// retain q+out (exactly 256MB) for k_attn.
#define GLOAD4NT(dst, base, vo) \
    asm volatile("global_load_dwordx4 %0, %1, %2 nt" \
                 : "=v"(dst) : "v"(vo), "s"(base) : "memory")
#define WAITV(n) asm volatile("s_waitcnt vmcnt(" #n ")" ::: "memory")
#define SBAR() __builtin_amdgcn_sched_barrier(0)

__device__ __forceinline__ void gload_lds16(const float4* g, void* l) {
    __builtin_amdgcn_global_load_lds(
        (const __attribute__((address_space(1))) unsigned int*)(const void*)g,
        (__attribute__((address_space(3))) unsigned int*)l, 16, 0, 0);
}

// ---------------- kernel 1 phase 1: grid-stride mean reduction of k, v ----------
// Structure identical to R8 (grid-stride, 16 outstanding asm dwordx4, static
// bins) -- ONLY change is the nt flag, for clean attribution.
__global__ __launch_bounds__(256, 1) void k_reduce_p1(const float4* __restrict__ k4,
                                                      const float4* __restrict__ v4,
                                                      float4* __restrict__ p4) {
    __shared__ float4 red[256];
    const int t = threadIdx.x;
    const int b = blockIdx.x;          // 0..1023
    const bool isv = (b >= 512);
    const int bb = b & 511;
    const float4* __restrict__ src = isv ? v4 : k4;
    const unsigned vbase = (unsigned)(bb * 256 + t) * 16u;   // byte offset

    float4 a0, a1, a2, a3, a4, a5, a6, a7;
    float4 b0, b1, b2, b3, b4, b5, b6, b7;
    float4 z = make_float4(0.f, 0.f, 0.f, 0.f);
    float4 acc0 = z, acc1 = z, acc2 = z, acc3 = z;

    // load j = g*8+i covers f4 index j*131072 + bb*256 + t  (2MB grid stripe)
#define OFF(g, i) (vbase + (unsigned)(((g) * 8 + (i)) * 2097152u))
#define ISSUE(G, g) \
    GLOAD4NT(G##0, src, OFF(g, 0)); GLOAD4NT(G##1, src, OFF(g, 1)); \
    GLOAD4NT(G##2, src, OFF(g, 2)); GLOAD4NT(G##3, src, OFF(g, 3)); \
    GLOAD4NT(G##4, src, OFF(g, 4)); GLOAD4NT(G##5, src, OFF(g, 5)); \
    GLOAD4NT(G##6, src, OFF(g, 6)); GLOAD4NT(G##7, src, OFF(g, 7))
#define CONSUME_A() \
    ADD4(acc0, a0); ADD4(acc1, a1); ADD4(acc2, a2); ADD4(acc3, a3); \
    ADD4(acc0, a4); ADD4(acc1, a5); ADD4(acc2, a6); ADD4(acc3, a7)
#define CONSUME_B() \
    ADD4(acc0, b0); ADD4(acc1, b1); ADD4(acc2, b2); ADD4(acc3, b3); \
    ADD4(acc0, b4); ADD4(acc1, b5); ADD4(acc2, b6); ADD4(acc3, b7)

    ISSUE(a, 0);  ISSUE(b, 1);                      // outstanding: 16
    WAITV(8); SBAR(); CONSUME_A(); ISSUE(a, 2);
    WAITV(8); SBAR(); CONSUME_B(); ISSUE(b, 3);
    WAITV(8); SBAR(); CONSUME_A(); ISSUE(a, 4);
    WAITV(8); SBAR(); CONSUME_B(); ISSUE(b, 5);
    WAITV(8); SBAR(); CONSUME_A(); ISSUE(a, 6);
    WAITV(8); SBAR(); CONSUME_B(); ISSUE(b, 7);
    WAITV(8); SBAR(); CONSUME_A();                  // group 6
    WAITV(0); SBAR(); CONSUME_B();                  // group 7

    ADD4(acc0, acc1);
    ADD4(acc2, acc3);
    ADD4(acc0, acc2);
    red[t] = acc0;               // bin: cc=(t>>5)&3 (col%4), q=t&31 (channel quad)
    __syncthreads();

    if (t < 128) {               // t and t+128 share (cc, q)
        float4 s = red[t];
        const float4 p = red[t + 128];
        ADD4(s, p);
        p4[(isv ? 65536 : 0) + bb * 128 + t] = s;   // slot t = cc*32 + q
    }
}

// ---------------- kernel 1 phase 2 (fused prep): partials -> k2/v2 ----------------
__global__ __launch_bounds__(256) void k_finish(const float4* __restrict__ p4,
                                                const float* __restrict__ logit_scale,
                                                float4* __restrict__ k2f4,
                                                float4* __restrict__ v2f4) {
    __shared__ float4 lsum[256];
    const int b = blockIdx.x;
    const int srcv = b >> 4;
    const int rc = (b >> 2) & 3;
    const int cc = b & 3;
    const int n = rc * 4 + cc;
    const int t = threadIdx.x;
    const int w0 = t >> 5;
    const int q = t & 31;

    const float4* base = p4 + srcv * 65536 + cc * 32 + q;
    float4 s = make_float4(0.f, 0.f, 0.f, 0.f);
#pragma unroll
    for (int b1 = 0; b1 < 2; ++b1) {
#pragma unroll
        for (int j = 0; j < 8; ++j) {
            const int bb = b1 * 256 + rc * 64 + w0 * 8 + j;
            const float4 x = base[bb * 128];
            ADD4(s, x);
        }
    }
    lsum[t] = s;
    __syncthreads();

    if (t < 32) {
        float4 m = lsum[t];
#pragma unroll
        for (int w = 1; w < 8; ++w) {
            const float4 x = lsum[w * 32 + t];
            ADD4(m, x);
        }
        const float inv = 1.0f / 16384.0f;
        m.x *= inv; m.y *= inv; m.z *= inv; m.w *= inv;

        const int h = t >> 3;        // head of this channel-quad
        const int dq = t & 7;        // d-quad within head
        if (srcv == 0) {
            float ss = m.x * m.x + m.y * m.y + m.z * m.z + m.w * m.w;
            ss += dppf<DPP_XOR1>(ss);
            ss += dppf<DPP_XOR2>(ss);
            ss += dppf<DPP_MIR8>(ss);   // per-head sum over its 8 lanes
            const float sc = __expf(fminf(logit_scale[h], 4.6051702f)); // log(1/0.01)
            const float f = sc / fmaxf(sqrtf(ss), 1e-12f);
            k2f4[h * 128 + n * 8 + dq] = make_float4(m.x * f, m.y * f, m.z * f, m.w * f);
        } else {
            v2f4[h * 128 + n * 8 + dq] = m;
        }
    }
}

// ---------------- fallback (ws too small): atomic version + prep ----------------
__global__ __launch_bounds__(256) void k_reduce_atomic(const float4* __restrict__ k4,
                                                       const float4* __restrict__ v4,
                                                       float* __restrict__ ksum,
                                                       float* __restrict__ vsum) {
    __shared__ float4 stage[2048];
    __shared__ float4 redE[256];
    __shared__ float4 redO[256];
    const int t = threadIdx.x;
    const int b = blockIdx.x;
    const bool isv = (b >= 1024);
    const int bb = b & 1023;
    const float4* __restrict__ src = isv ? v4 : k4;
    float* __restrict__ dst = isv ? vsum : ksum;

    const int wv = t >> 6;
    const int ln = t & 63;
    const long gstart = (long)bb * 8192 + wv * 2048;
    const float4* gsrc = src + gstart + ln;
    char* lbase = (char*)stage + wv * 8192;

#pragma unroll
    for (int j = 0; j < 4; ++j)
        gload_lds16(gsrc + j * 64, lbase + j * 1024);

    float4 z = make_float4(0.f, 0.f, 0.f, 0.f);
    float4 accE = z, accO = z;

#pragma unroll
    for (int c = 0; c < 8; ++c) {
        if (c < 7) {
            const int p1 = (c + 1) & 1;
#pragma unroll
            for (int j = 0; j < 4; ++j)
                gload_lds16(gsrc + (c + 1) * 256 + j * 64,
                            lbase + p1 * 4096 + j * 1024);
            asm volatile("s_waitcnt vmcnt(4)" ::: "memory");
        } else {
            asm volatile("s_waitcnt vmcnt(0)" ::: "memory");
        }
        __builtin_amdgcn_sched_barrier(0);
        const int p = c & 1;
        const float4* lf = (const float4*)(lbase + p * 4096) + ln;
        const float4 x0 = lf[0];
        const float4 x1 = lf[64];
        const float4 x2 = lf[128];
        const float4 x3 = lf[192];
        ADD4(accE, x0); ADD4(accO, x1); ADD4(accE, x2); ADD4(accO, x3);
    }

    redE[wv * 64 + ln] = accE;
    redO[wv * 64 + ln] = accO;
    __syncthreads();

    if (t < 128) {
        const int n0 = t >> 5;
        const int c4 = t & 31;
        const float4* arr = (n0 < 2) ? redE : redO;
        const int base = (n0 & 1) * 32 + c4;
        float4 s = arr[base];
        const float4 s1 = arr[base + 64];
        const float4 s2 = arr[base + 128];
        const float4 s3 = arr[base + 192];
        ADD4(s, s1); ADD4(s, s2); ADD4(s, s3);
        const int n = ((bb >> 1) & 3) * 4 + n0;
        const int c = c4 * 4;
        atomicAdd(&dst[n * 128 + c + 0], s.x);
        atomicAdd(&dst[n * 128 + c + 1], s.y);
        atomicAdd(&dst[n * 128 + c + 2], s.z);
        atomicAdd(&dst[n * 128 + c + 3], s.w);
    }
}

__global__ __launch_bounds__(256) void k_prep(const float* __restrict__ ksum,
                                              const float* __restrict__ vsum,
                                              const float* __restrict__ logit_scale,
                                              float* __restrict__ k2,
                                              float* __restrict__ v2) {
    __shared__ float mk[2048], mv[2048], fac[64];
    const int t = threadIdx.x;
    const float inv = 1.0f / 16384.0f;
    for (int w = t; w < 2048; w += 256) {
        mk[w] = ksum[w] * inv;
        mv[w] = vsum[w] * inv;
    }
    __syncthreads();
    if (t < 64) {
        const int h = t >> 4, n = t & 15;
        float ss = 0.f;
#pragma unroll
        for (int d = 0; d < 32; ++d) {
            float x = mk[n * 128 + h * 32 + d];
            ss += x * x;
        }
        const float nrm = sqrtf(ss);
        const float sc = __expf(fminf(logit_scale[h], 4.6051702f));
        fac[t] = sc / fmaxf(nrm, 1e-12f);
    }
    __syncthreads();
    for (int w = t; w < 2048; w += 256) {
        const int h = w >> 9;
        const int n = (w & 511) >> 5;
        const int d = w & 31;
        const float f = fac[h * 16 + n];
        k2[w] = mk[n * 128 + h * 32 + d] * f;
        v2[w] = mv[n * 128 + h * 32 + d];
    }
}

// ---------------- kernel 2: per-query attention (at roofline - unchanged) ----
__global__ __launch_bounds__(256, 2) void k_attn(const float4* __restrict__ q4,
                                                 const float2* __restrict__ mask2,
                                                 const float4* __restrict__ k2f4,
                                                 const float4* __restrict__ v2f4,
                                                 float4* __restrict__ out4) {
    const int t = threadIdx.x;
    const int isub = t >> 5;       // 0..7
    const int l5 = t & 31;
    const int h = l5 >> 3;         // head
    const int g = l5 & 7;          // d-quad within head

    float4 kreg[16], vreg[16];
#pragma unroll
    for (int n = 0; n < 16; ++n) {
        kreg[n] = k2f4[h * 128 + n * 8 + g];
        vreg[n] = v2f4[h * 128 + n * 8 + g];
    }

    const bool b2 = (g & 4) != 0;
    const bool b1 = (g & 2) != 0;
    const bool b0 = (g & 1) != 0;

    auto process = [&](const float4 qv, const float2 mw) -> float4 {
        float ss = qv.x * qv.x + qv.y * qv.y + qv.z * qv.z + qv.w * qv.w;
        ss += dppf<DPP_XOR1>(ss);
        ss += dppf<DPP_XOR2>(ss);
        ss += dppf<DPP_MIR8>(ss);
        const float rn = rsqrtf(fmaxf(ss, 1e-24f));
        const float qx = qv.x * rn, qy = qv.y * rn, qz = qv.z * rn, qw = qv.w * rn;

        float part[16];
#pragma unroll
        for (int n = 0; n < 16; ++n)
            part[n] = qx * kreg[n].x + qy * kreg[n].y + qz * kreg[n].z + qw * kreg[n].w;

        float r8[8];
#pragma unroll
        for (int j = 0; j < 8; ++j) {
            const float snd = b2 ? part[j] : part[j + 8];
            const float kp  = b2 ? part[j + 8] : part[j];
            r8[j] = kp + dppf<DPP_MIR8>(snd);
        }
        float r4[4];
#pragma unroll
        for (int j = 0; j < 4; ++j) {
            const float snd = b1 ? r8[j] : r8[j + 4];
            const float kp  = b1 ? r8[j + 4] : r8[j];
            r4[j] = kp + dppf<DPP_XOR2>(snd);
        }
        float s0, s1;
        {
            const float sndA = b0 ? r4[0] : r4[2];
            const float kpA  = b0 ? r4[2] : r4[0];
            s0 = kpA + dppf<DPP_XOR1>(sndA);
            const float sndB = b0 ? r4[1] : r4[3];
            const float kpB  = b0 ? r4[3] : r4[1];
            s1 = kpB + dppf<DPP_XOR1>(sndB);
        }

        const float e0 = __expf(s0 + mw.x);
        const float e1 = __expf(s1 + mw.y);

        float ds = e0 + e1;
        ds += dppf<DPP_XOR1>(ds);
        ds += dppf<DPP_XOR2>(ds);
        ds += dppf<DPP_MIR8>(ds);
        const float rden = 1.0f / ds;

        float pf[16];
        pf[0]  = swzf<(0 << 5) | 0x18>(e0);
        pf[1]  = swzf<(0 << 5) | 0x18>(e1);
        pf[2]  = swzf<(1 << 5) | 0x18>(e0);
        pf[3]  = swzf<(1 << 5) | 0x18>(e1);
        pf[4]  = swzf<(2 << 5) | 0x18>(e0);
        pf[5]  = swzf<(2 << 5) | 0x18>(e1);
        pf[6]  = swzf<(3 << 5) | 0x18>(e0);
        pf[7]  = swzf<(3 << 5) | 0x18>(e1);
        pf[8]  = swzf<(4 << 5) | 0x18>(e0);
        pf[9]  = swzf<(4 << 5) | 0x18>(e1);
        pf[10] = swzf<(5 << 5) | 0x18>(e0);
        pf[11] = swzf<(5 << 5) | 0x18>(e1);
        pf[12] = swzf<(6 << 5) | 0x18>(e0);
        pf[13] = swzf<(6 << 5) | 0x18>(e1);
        pf[14] = swzf<(7 << 5) | 0x18>(e0);
        pf[15] = swzf<(7 << 5) | 0x18>(e1);

        float ox = 0.f, oy = 0.f, oz = 0.f, ow = 0.f;
#pragma unroll
        for (int n = 0; n < 16; ++n) {
            ox += pf[n] * vreg[n].x;
            oy += pf[n] * vreg[n].y;
            oz += pf[n] * vreg[n].z;
            ow += pf[n] * vreg[n].w;
        }
        return make_float4(ox * rden, oy * rden, oz * rden, ow * rden);
    };

    int i = blockIdx.x * 128 + isub;   // queries i and i+8 per iter, stride 16
    float4 qA = q4[i * 32 + h * 8 + g];
    float4 qB = q4[(i + 8) * 32 + h * 8 + g];
    float2 mA = mask2[i * 8 + g];
    float2 mB = mask2[(i + 8) * 8 + g];

#pragma unroll 1
    for (int iter = 0; iter < 8; ++iter) {
        const int ip = (iter < 7) ? (i + 16) : i;   // branchless prefetch (clamped)
        const float4 qA_n = q4[ip * 32 + h * 8 + g];
        const float4 qB_n = q4[(ip + 8) * 32 + h * 8 + g];
        const float2 mA_n = mask2[ip * 8 + g];
        const float2 mB_n = mask2[(ip + 8) * 8 + g];

        const float4 oA = process(qA, mA);
        const float4 oB = process(qB, mB);
        out4[i * 32 + h * 8 + g] = oA;
        out4[(i + 8) * 32 + h * 8 + g] = oB;

        i += 16;
        qA = qA_n; qB = qB_n; mA = mA_n; mB = mB_n;
    }
}

extern "C" void kernel_launch(void* const* d_in, const int* in_sizes, int n_in,
                              void* d_out, int out_size, void* d_ws, size_t ws_size,
                              hipStream_t stream) {
    (void)in_sizes; (void)n_in; (void)out_size;
    const float* q = (const float*)d_in[0];
    const float* k = (const float*)d_in[1];
    const float* v = (const float*)d_in[2];
    const float* mask = (const float*)d_in[5];
    const float* ls = (const float*)d_in[6];

    float* ws = (float*)d_ws;
    float* ksum = ws;
    float* vsum = ws + 2048;
    float* k2 = ws + 4096;
    float* v2 = ws + 6144;
    float* part = ws + 8192;   // 131072 float4 = 2MB

    const size_t needed = (size_t)8192 * 4 + (size_t)131072 * 16;
    if (ws_size >= needed) {
        k_reduce_p1<<<1024, 256, 0, stream>>>((const float4*)k, (const float4*)v,
                                              (float4*)part);
        k_finish<<<32, 256, 0, stream>>>((const float4*)part, ls,
                                         (float4*)k2, (float4*)v2);
    } else {
        hipMemsetAsync(ws, 0, 4096 * sizeof(float), stream);
        k_reduce_atomic<<<2048, 256, 0, stream>>>((const float4*)k, (const float4*)v,
                                                  ksum, vsum);
        k_prep<<<1, 256, 0, stream>>>(ksum, vsum, ls, k2, v2);
    }
    k_attn<<<2048, 256, 0, stream>>>((const float4*)q, (const float2*)mask,
                                     (const float4*)k2, (const float4*)v2,
                                     (float4*)d_out);
}

// Round 10
// 99.633 us; speedup vs baseline: 1.5493x; 1.1964x over previous
//
#include <hip/hip_runtime.h>

// Problem constants: Q=262144, L=512*512, C=128, window 4x4 -> N=16, 4 heads x 32d. B=1.
// ws float layout: [0,2048) ksum (fallback), [2048,4096) vsum (fallback),
//   [4096,5120) k2b: bf16 A-frags, 4 heads x 64 lanes x 16B
//   [5120,7168) v2b: bf16 B-frags, (4 heads x 2 dhalves) x 64 lanes x 16B (keys>=16 zeroed)
//   [6144,8192) fallback k2/v2 f32 (exclusive with main path)
//   [8192,532480) partials p4 (2MB)

typedef __attribute__((ext_vector_type(8))) short bf16x8;
typedef __attribute__((ext_vector_type(4))) float f32x4;
union F4S8 { float4 f; bf16x8 s; };

// ---------------- DPP / swizzle helpers ----------------
template <int CTRL>
__device__ __forceinline__ float dppf(float x) {
    return __int_as_float(
        __builtin_amdgcn_update_dpp(0, __float_as_int(x), CTRL, 0xF, 0xF, true));
}
#define DPP_XOR1 0xB1
#define DPP_XOR2 0x4E
#define DPP_MIR8 0x141

template <int IMM>
__device__ __forceinline__ float swzf(float x) {
    return __int_as_float(__builtin_amdgcn_ds_swizzle(__float_as_int(x), IMM));
}

#define ADD4(A, B) { A.x += B.x; A.y += B.y; A.z += B.z; A.w += B.w; }

#define GLOAD4NT(dst, base, vo) \
    asm volatile("global_load_dwordx4 %0, %1, %2 nt" \
                 : "=v"(dst) : "v"(vo), "s"(base) : "memory")
#define WAITV(n) asm volatile("s_waitcnt vmcnt(" #n ")" ::: "memory")
#define SBAR() __builtin_amdgcn_sched_barrier(0)

__device__ __forceinline__ void gload_lds16(const float4* g, void* l) {
    __builtin_amdgcn_global_load_lds(
        (const __attribute__((address_space(1))) unsigned int*)(const void*)g,
        (__attribute__((address_space(3))) unsigned int*)l, 16, 0, 0);
}

__device__ __forceinline__ unsigned short bf16rne(float x) {
    unsigned u = __float_as_uint(x);
    return (unsigned short)((u + 0x7fffu + ((u >> 16) & 1u)) >> 16);
}
__device__ __forceinline__ unsigned cvtpk_bf16(float lo, float hi) {
    unsigned r;
    asm("v_cvt_pk_bf16_f32 %0, %1, %2" : "=v"(r) : "v"(lo), "v"(hi));
    return r;
}

// ---------------- kernel 1 phase 1: grid-stride NT mean reduction (R9, working) ----
__global__ __launch_bounds__(256, 1) void k_reduce_p1(const float4* __restrict__ k4,
                                                      const float4* __restrict__ v4,
                                                      float4* __restrict__ p4) {
    __shared__ float4 red[256];
    const int t = threadIdx.x;
    const int b = blockIdx.x;          // 0..1023
    const bool isv = (b >= 512);
    const int bb = b & 511;
    const float4* __restrict__ src = isv ? v4 : k4;
    const unsigned vbase = (unsigned)(bb * 256 + t) * 16u;

    float4 a0, a1, a2, a3, a4, a5, a6, a7;
    float4 b0, b1, b2, b3, b4, b5, b6, b7;
    float4 z = make_float4(0.f, 0.f, 0.f, 0.f);
    float4 acc0 = z, acc1 = z, acc2 = z, acc3 = z;

#define OFF(g, i) (vbase + (unsigned)(((g) * 8 + (i)) * 2097152u))
#define ISSUE(G, g) \
    GLOAD4NT(G##0, src, OFF(g, 0)); GLOAD4NT(G##1, src, OFF(g, 1)); \
    GLOAD4NT(G##2, src, OFF(g, 2)); GLOAD4NT(G##3, src, OFF(g, 3)); \
    GLOAD4NT(G##4, src, OFF(g, 4)); GLOAD4NT(G##5, src, OFF(g, 5)); \
    GLOAD4NT(G##6, src, OFF(g, 6)); GLOAD4NT(G##7, src, OFF(g, 7))
#define CONSUME_A() \
    ADD4(acc0, a0); ADD4(acc1, a1); ADD4(acc2, a2); ADD4(acc3, a3); \
    ADD4(acc0, a4); ADD4(acc1, a5); ADD4(acc2, a6); ADD4(acc3, a7)
#define CONSUME_B() \
    ADD4(acc0, b0); ADD4(acc1, b1); ADD4(acc2, b2); ADD4(acc3, b3); \
    ADD4(acc0, b4); ADD4(acc1, b5); ADD4(acc2, b6); ADD4(acc3, b7)

    ISSUE(a, 0);  ISSUE(b, 1);
    WAITV(8); SBAR(); CONSUME_A(); ISSUE(a, 2);
    WAITV(8); SBAR(); CONSUME_B(); ISSUE(b, 3);
    WAITV(8); SBAR(); CONSUME_A(); ISSUE(a, 4);
    WAITV(8); SBAR(); CONSUME_B(); ISSUE(b, 5);
    WAITV(8); SBAR(); CONSUME_A(); ISSUE(a, 6);
    WAITV(8); SBAR(); CONSUME_B(); ISSUE(b, 7);
    WAITV(8); SBAR(); CONSUME_A();
    WAITV(0); SBAR(); CONSUME_B();

    ADD4(acc0, acc1);
    ADD4(acc2, acc3);
    ADD4(acc0, acc2);
    red[t] = acc0;
    __syncthreads();

    if (t < 128) {
        float4 s = red[t];
        const float4 p = red[t + 128];
        ADD4(s, p);
        p4[(isv ? 65536 : 0) + bb * 128 + t] = s;
    }
}

// ---------------- kernel 1 phase 2: partials -> packed bf16 MFMA fragments ----
// 32 blocks. b: srcv=b>>4, rc=(b>>2)&3, cc=b&3; n = rc*4+cc (the key index).
// Reduction identical to R9; then:
//  K-side: per-head L2norm+scale fold, pack A-frags k2b[h][lane l]: lane l holds
//    key=l&15(=n), dims (l>>4)*8+j as 8 bf16 (16B). Block writes lanes n+16*lg.
//  V-side: pack B-frags (K=32, keys>=16 zero): v2b[(h,hf)][l]: lane l holds
//    k=(l>>4)*8+j, d=hf*16+(l&15). Block n writes j=n&7 slots of lanes (n>>3)*16+d,
//    plus its share of the zero-fill for lanes 32..63.
__global__ __launch_bounds__(256) void k_finish(const float4* __restrict__ p4,
                                                const float* __restrict__ logit_scale,
                                                float4* __restrict__ k2bf4,
                                                float* __restrict__ v2b_base) {
    __shared__ float4 lsum[256];
    __shared__ unsigned short kb16[128];
    __shared__ float vb32[128];
    const int b = blockIdx.x;
    const int srcv = b >> 4;
    const int rc = (b >> 2) & 3;
    const int cc = b & 3;
    const int n = rc * 4 + cc;
    const int t = threadIdx.x;
    const int w0 = t >> 5;
    const int q = t & 31;

    const float4* base = p4 + srcv * 65536 + cc * 32 + q;
    float4 s = make_float4(0.f, 0.f, 0.f, 0.f);
#pragma unroll
    for (int b1 = 0; b1 < 2; ++b1) {
#pragma unroll
        for (int j = 0; j < 8; ++j) {
            const int bb = b1 * 256 + rc * 64 + w0 * 8 + j;
            const float4 x = base[bb * 128];
            ADD4(s, x);
        }
    }
    lsum[t] = s;
    __syncthreads();

    if (t < 32) {
        float4 m = lsum[t];
#pragma unroll
        for (int w = 1; w < 8; ++w) {
            const float4 x = lsum[w * 32 + t];
            ADD4(m, x);
        }
        const float inv = 1.0f / 16384.0f;
        m.x *= inv; m.y *= inv; m.z *= inv; m.w *= inv;

        if (srcv == 0) {
            const int h = t >> 3;        // head of this channel-quad
            float ss = m.x * m.x + m.y * m.y + m.z * m.z + m.w * m.w;
            ss += dppf<DPP_XOR1>(ss);
            ss += dppf<DPP_XOR2>(ss);
            ss += dppf<DPP_MIR8>(ss);    // per-head sum over its 8 lanes
            const float sc = __expf(fminf(logit_scale[h], 4.6051702f)); // log(1/0.01)
            const float f = sc / fmaxf(sqrtf(ss), 1e-12f);
            kb16[4 * t + 0] = bf16rne(m.x * f);
            kb16[4 * t + 1] = bf16rne(m.y * f);
            kb16[4 * t + 2] = bf16rne(m.z * f);
            kb16[4 * t + 3] = bf16rne(m.w * f);
        } else {
            vb32[4 * t + 0] = m.x;
            vb32[4 * t + 1] = m.y;
            vb32[4 * t + 2] = m.z;
            vb32[4 * t + 3] = m.w;
        }
    }
    __syncthreads();

    if (srcv == 0) {
        if (t < 16) {
            const int h = t >> 2, lg = t & 3;
            const uint4* kb4 = (const uint4*)kb16;   // 8 ushorts per uint4
            const uint4 rec = kb4[h * 4 + lg];       // channels h*32+lg*8 .. +7
            k2bf4[h * 64 + n + lg * 16] = make_float4(
                __uint_as_float(rec.x), __uint_as_float(rec.y),
                __uint_as_float(rec.z), __uint_as_float(rec.w));
        }
    } else {
        unsigned short* v2u16 = (unsigned short*)v2b_base;
        unsigned* v2u32 = (unsigned*)v2b_base;
        if (t < 128) {
            const int h = t >> 5, hf = (t >> 4) & 1, d = t & 15;
            const int l = (n >> 3) * 16 + d;
            const int j = n & 7;
            v2u16[((h * 2 + hf) * 64 + l) * 8 + j] = bf16rne(vb32[h * 32 + hf * 16 + d]);
        }
        if (t < 64) {   // zero-fill lanes 32..63 (keys 16..31): block n covers 64 u32
            const int gi = n * 64 + t;           // 0..1023
            const int fg = gi >> 7;              // frag group 0..7
            const int rem = gi & 127;
            const int l2 = 32 + (rem >> 2);
            const int c = rem & 3;
            v2u32[(fg * 64 + l2) * 4 + c] = 0u;
        }
    }
}

// ---------------- kernel 2: MFMA attention ----------------
// 4096 blocks x 256 thr; wave gw handles queries [gw*16, gw*16+16), all 4 heads.
// lane l: query col ql=l&15, group g4=l>>4.
// QK: S^T[key][q] = mfma_f32_16x16x32_bf16(A=K2 frags, B=qhat frags) ->
//   lane holds S^T[g4*4+r][ql] (C/D layout, HW-verified). Softmax: 4 exps/lane,
//   denom = 4-sum + shfl_xor(16,32). P lands natively in the PV A-frag slots;
//   gather to K=32 A-frag via 4 shfl (keys>=16 garbage annihilated by V zeros).
// PV: O = mfma(A=P, B=Vfrag) twice (d halves). nt stores (L3 keeps q+mask).
__global__ __launch_bounds__(256) void k_attn_mfma(const float4* __restrict__ q4,
                                                   const float4* __restrict__ mask4,
                                                   const float4* __restrict__ k2b,
                                                   const float4* __restrict__ v2b,
                                                   float* __restrict__ outp) {
    const int tid = threadIdx.x;
    const int l = tid & 63, wv = tid >> 6;
    const int gw = blockIdx.x * 4 + wv;          // 0..16383
    const int ql = l & 15, g4 = l >> 4;
    const int qq = gw * 16 + ql;

    // K2 A-frags + V B-frags (L2-hot, 12KB shared by all waves)
    F4S8 kb[4];
    F4S8 vb[8];
#pragma unroll
    for (int h = 0; h < 4; ++h) kb[h].f = k2b[h * 64 + l];
#pragma unroll
    for (int i = 0; i < 8; ++i) vb[i].f = v2b[i * 64 + l];

    // Q fp32: per head dims g4*8 .. +7 (two float4)
    float4 qa[4], qb[4];
#pragma unroll
    for (int h = 0; h < 4; ++h) {
        qa[h] = q4[qq * 32 + h * 8 + g4 * 2];
        qb[h] = q4[qq * 32 + h * 8 + g4 * 2 + 1];
    }
    const float4 mk = mask4[qq * 4 + g4];        // mask[qq][g4*4 .. +3]

    const f32x4 z4 = {0.f, 0.f, 0.f, 0.f};
    const int src0 = ql + g4 * 32;               // P-gather source lanes
    const int src1 = src0 + 16;

#pragma unroll
    for (int h = 0; h < 4; ++h) {
        // ---- q norm over the 32-dim head ----
        float ss = qa[h].x * qa[h].x + qa[h].y * qa[h].y + qa[h].z * qa[h].z + qa[h].w * qa[h].w
                 + qb[h].x * qb[h].x + qb[h].y * qb[h].y + qb[h].z * qb[h].z + qb[h].w * qb[h].w;
        ss += __shfl_xor(ss, 16, 64);
        ss += __shfl_xor(ss, 32, 64);
        const float rn = rsqrtf(fmaxf(ss, 1e-24f));

        // ---- pack qhat to bf16x8 B-frag ----
        F4S8 af;
        af.f = make_float4(
            __uint_as_float(cvtpk_bf16(qa[h].x * rn, qa[h].y * rn)),
            __uint_as_float(cvtpk_bf16(qa[h].z * rn, qa[h].w * rn)),
            __uint_as_float(cvtpk_bf16(qb[h].x * rn, qb[h].y * rn)),
            __uint_as_float(cvtpk_bf16(qb[h].z * rn, qb[h].w * rn)));

        // ---- S^T = K2 . Qhat^T ----
        f32x4 st = __builtin_amdgcn_mfma_f32_16x16x32_bf16(kb[h].s, af.s, z4, 0, 0, 0);

        // ---- softmax (lane holds keys g4*4+r of query ql) ----
        const float e0 = __expf(st[0] + mk.x);
        const float e1 = __expf(st[1] + mk.y);
        const float e2 = __expf(st[2] + mk.z);
        const float e3 = __expf(st[3] + mk.w);
        float ds = (e0 + e1) + (e2 + e3);
        ds += __shfl_xor(ds, 16, 64);
        ds += __shfl_xor(ds, 32, 64);
        const float rden = 1.0f / ds;

        const unsigned a01 = cvtpk_bf16(e0 * rden, e1 * rden);
        const unsigned a23 = cvtpk_bf16(e2 * rden, e3 * rden);

        // ---- gather P into K=32 A-frag: elem j -> P[ql][g4*8+j] (g4>=2 garbage, V=0) ----
        const unsigned u0 = (unsigned)__shfl((int)a01, src0 & 63, 64);
        const unsigned u1 = (unsigned)__shfl((int)a23, src0 & 63, 64);
        const unsigned u2 = (unsigned)__shfl((int)a01, src1 & 63, 64);
        const unsigned u3 = (unsigned)__shfl((int)a23, src1 & 63, 64);
        F4S8 pa;
        pa.f = make_float4(__uint_as_float(u0), __uint_as_float(u1),
                           __uint_as_float(u2), __uint_as_float(u3));

        // ---- O = P . V  (two d-halves) ----
        f32x4 olo = __builtin_amdgcn_mfma_f32_16x16x32_bf16(pa.s, vb[h * 2 + 0].s, z4, 0, 0, 0);
        f32x4 ohi = __builtin_amdgcn_mfma_f32_16x16x32_bf16(pa.s, vb[h * 2 + 1].s, z4, 0, 0, 0);

        // ---- store: lane holds O[q=gw*16+g4*4+r][d=hf*16+ql] of head h ----
        float* ob = outp + (size_t)(gw * 16 + g4 * 4) * 128 + h * 32 + ql;
#pragma unroll
        for (int r = 0; r < 4; ++r) {
            __builtin_nontemporal_store(olo[r], ob + r * 128);
            __builtin_nontemporal_store(ohi[r], ob + r * 128 + 16);
        }
    }
}

// ---------------- fallback (ws too small): atomic + prep + f32 attn ----------------
__global__ __launch_bounds__(256) void k_reduce_atomic(const float4* __restrict__ k4,
                                                       const float4* __restrict__ v4,
                                                       float* __restrict__ ksum,
                                                       float* __restrict__ vsum) {
    __shared__ float4 stage[2048];
    __shared__ float4 redE[256];
    __shared__ float4 redO[256];
    const int t = threadIdx.x;
    const int b = blockIdx.x;
    const bool isv = (b >= 1024);
    const int bb = b & 1023;
    const float4* __restrict__ src = isv ? v4 : k4;
    float* __restrict__ dst = isv ? vsum : ksum;

    const int wv = t >> 6;
    const int ln = t & 63;
    const long gstart = (long)bb * 8192 + wv * 2048;
    const float4* gsrc = src + gstart + ln;
    char* lbase = (char*)stage + wv * 8192;

#pragma unroll
    for (int j = 0; j < 4; ++j)
        gload_lds16(gsrc + j * 64, lbase + j * 1024);

    float4 z = make_float4(0.f, 0.f, 0.f, 0.f);
    float4 accE = z, accO = z;

#pragma unroll
    for (int c = 0; c < 8; ++c) {
        if (c < 7) {
            const int p1 = (c + 1) & 1;
#pragma unroll
            for (int j = 0; j < 4; ++j)
                gload_lds16(gsrc + (c + 1) * 256 + j * 64,
                            lbase + p1 * 4096 + j * 1024);
            asm volatile("s_waitcnt vmcnt(4)" ::: "memory");
        } else {
            asm volatile("s_waitcnt vmcnt(0)" ::: "memory");
        }
        __builtin_amdgcn_sched_barrier(0);
        const int p = c & 1;
        const float4* lf = (const float4*)(lbase + p * 4096) + ln;
        const float4 x0 = lf[0];
        const float4 x1 = lf[64];
        const float4 x2 = lf[128];
        const float4 x3 = lf[192];
        ADD4(accE, x0); ADD4(accO, x1); ADD4(accE, x2); ADD4(accO, x3);
    }

    redE[wv * 64 + ln] = accE;
    redO[wv * 64 + ln] = accO;
    __syncthreads();

    if (t < 128) {
        const int n0 = t >> 5;
        const int c4 = t & 31;
        const float4* arr = (n0 < 2) ? redE : redO;
        const int base = (n0 & 1) * 32 + c4;
        float4 s = arr[base];
        const float4 s1 = arr[base + 64];
        const float4 s2 = arr[base + 128];
        const float4 s3 = arr[base + 192];
        ADD4(s, s1); ADD4(s, s2); ADD4(s, s3);
        const int n = ((bb >> 1) & 3) * 4 + n0;
        const int c = c4 * 4;
        atomicAdd(&dst[n * 128 + c + 0], s.x);
        atomicAdd(&dst[n * 128 + c + 1], s.y);
        atomicAdd(&dst[n * 128 + c + 2], s.z);
        atomicAdd(&dst[n * 128 + c + 3], s.w);
    }
}

__global__ __launch_bounds__(256) void k_prep(const float* __restrict__ ksum,
                                              const float* __restrict__ vsum,
                                              const float* __restrict__ logit_scale,
                                              float* __restrict__ k2,
                                              float* __restrict__ v2) {
    __shared__ float mk[2048], mv[2048], fac[64];
    const int t = threadIdx.x;
    const float inv = 1.0f / 16384.0f;
    for (int w = t; w < 2048; w += 256) {
        mk[w] = ksum[w] * inv;
        mv[w] = vsum[w] * inv;
    }
    __syncthreads();
    if (t < 64) {
        const int h = t >> 4, n = t & 15;
        float ss = 0.f;
#pragma unroll
        for (int d = 0; d < 32; ++d) {
            float x = mk[n * 128 + h * 32 + d];
            ss += x * x;
        }
        const float nrm = sqrtf(ss);
        const float sc = __expf(fminf(logit_scale[h], 4.6051702f));
        fac[t] = sc / fmaxf(nrm, 1e-12f);
    }
    __syncthreads();
    for (int w = t; w < 2048; w += 256) {
        const int h = w >> 9;
        const int n = (w & 511) >> 5;
        const int d = w & 31;
        const float f = fac[h * 16 + n];
        k2[w] = mk[n * 128 + h * 32 + d] * f;
        v2[w] = mv[n * 128 + h * 32 + d];
    }
}

__global__ __launch_bounds__(256, 2) void k_attn(const float4* __restrict__ q4,
                                                 const float2* __restrict__ mask2,
                                                 const float4* __restrict__ k2f4,
                                                 const float4* __restrict__ v2f4,
                                                 float4* __restrict__ out4) {
    const int t = threadIdx.x;
    const int isub = t >> 5;
    const int l5 = t & 31;
    const int h = l5 >> 3;
    const int g = l5 & 7;

    float4 kreg[16], vreg[16];
#pragma unroll
    for (int n = 0; n < 16; ++n) {
        kreg[n] = k2f4[h * 128 + n * 8 + g];
        vreg[n] = v2f4[h * 128 + n * 8 + g];
    }

    const bool b2 = (g & 4) != 0;
    const bool b1 = (g & 2) != 0;
    const bool b0 = (g & 1) != 0;

    auto process = [&](const float4 qv, const float2 mw) -> float4 {
        float ss = qv.x * qv.x + qv.y * qv.y + qv.z * qv.z + qv.w * qv.w;
        ss += dppf<DPP_XOR1>(ss);
        ss += dppf<DPP_XOR2>(ss);
        ss += dppf<DPP_MIR8>(ss);
        const float rn = rsqrtf(fmaxf(ss, 1e-24f));
        const float qx = qv.x * rn, qy = qv.y * rn, qz = qv.z * rn, qw = qv.w * rn;

        float part[16];
#pragma unroll
        for (int n = 0; n < 16; ++n)
            part[n] = qx * kreg[n].x + qy * kreg[n].y + qz * kreg[n].z + qw * kreg[n].w;

        float r8[8];
#pragma unroll
        for (int j = 0; j < 8; ++j) {
            const float snd = b2 ? part[j] : part[j + 8];
            const float kp  = b2 ? part[j + 8] : part[j];
            r8[j] = kp + dppf<DPP_MIR8>(snd);
        }
        float r4[4];
#pragma unroll
        for (int j = 0; j < 4; ++j) {
            const float snd = b1 ? r8[j] : r8[j + 4];
            const float kp  = b1 ? r8[j + 4] : r8[j];
            r4[j] = kp + dppf<DPP_XOR2>(snd);
        }
        float s0, s1;
        {
            const float sndA = b0 ? r4[0] : r4[2];
            const float kpA  = b0 ? r4[2] : r4[0];
            s0 = kpA + dppf<DPP_XOR1>(sndA);
            const float sndB = b0 ? r4[1] : r4[3];
            const float kpB  = b0 ? r4[3] : r4[1];
            s1 = kpB + dppf<DPP_XOR1>(sndB);
        }

        const float e0 = __expf(s0 + mw.x);
        const float e1 = __expf(s1 + mw.y);

        float ds = e0 + e1;
        ds += dppf<DPP_XOR1>(ds);
        ds += dppf<DPP_XOR2>(ds);
        ds += dppf<DPP_MIR8>(ds);
        const float rden = 1.0f / ds;

        float pf[16];
        pf[0]  = swzf<(0 << 5) | 0x18>(e0);
        pf[1]  = swzf<(0 << 5) | 0x18>(e1);
        pf[2]  = swzf<(1 << 5) | 0x18>(e0);
        pf[3]  = swzf<(1 << 5) | 0x18>(e1);
        pf[4]  = swzf<(2 << 5) | 0x18>(e0);
        pf[5]  = swzf<(2 << 5) | 0x18>(e1);
        pf[6]  = swzf<(3 << 5) | 0x18>(e0);
        pf[7]  = swzf<(3 << 5) | 0x18>(e1);
        pf[8]  = swzf<(4 << 5) | 0x18>(e0);
        pf[9]  = swzf<(4 << 5) | 0x18>(e1);
        pf[10] = swzf<(5 << 5) | 0x18>(e0);
        pf[11] = swzf<(5 << 5) | 0x18>(e1);
        pf[12] = swzf<(6 << 5) | 0x18>(e0);
        pf[13] = swzf<(6 << 5) | 0x18>(e1);
        pf[14] = swzf<(7 << 5) | 0x18>(e0);
        pf[15] = swzf<(7 << 5) | 0x18>(e1);

        float ox = 0.f, oy = 0.f, oz = 0.f, ow = 0.f;
#pragma unroll
        for (int n = 0; n < 16; ++n) {
            ox += pf[n] * vreg[n].x;
            oy += pf[n] * vreg[n].y;
            oz += pf[n] * vreg[n].z;
            ow += pf[n] * vreg[n].w;
        }
        return make_float4(ox * rden, oy * rden, oz * rden, ow * rden);
    };

    int i = blockIdx.x * 128 + isub;
    float4 qA = q4[i * 32 + h * 8 + g];
    float4 qB = q4[(i + 8) * 32 + h * 8 + g];
    float2 mA = mask2[i * 8 + g];
    float2 mB = mask2[(i + 8) * 8 + g];

#pragma unroll 1
    for (int iter = 0; iter < 8; ++iter) {
        const int ip = (iter < 7) ? (i + 16) : i;
        const float4 qA_n = q4[ip * 32 + h * 8 + g];
        const float4 qB_n = q4[(ip + 8) * 32 + h * 8 + g];
        const float2 mA_n = mask2[ip * 8 + g];
        const float2 mB_n = mask2[(ip + 8) * 8 + g];

        const float4 oA = process(qA, mA);
        const float4 oB = process(qB, mB);
        out4[i * 32 + h * 8 + g] = oA;
        out4[(i + 8) * 32 + h * 8 + g] = oB;

        i += 16;
        qA = qA_n; qB = qB_n; mA = mA_n; mB = mB_n;
    }
}

extern "C" void kernel_launch(void* const* d_in, const int* in_sizes, int n_in,
                              void* d_out, int out_size, void* d_ws, size_t ws_size,
                              hipStream_t stream) {
    (void)in_sizes; (void)n_in; (void)out_size;
    const float* q = (const float*)d_in[0];
    const float* k = (const float*)d_in[1];
    const float* v = (const float*)d_in[2];
    const float* mask = (const float*)d_in[5];
    const float* ls = (const float*)d_in[6];

    float* ws = (float*)d_ws;
    float* ksum = ws;
    float* vsum = ws + 2048;
    float* k2b = ws + 4096;    // 1024 floats: packed K2 A-frags
    float* v2b = ws + 5120;    // 2048 floats: packed V B-frags
    float* k2 = ws + 4096;     // fallback f32 (exclusive path)
    float* v2 = ws + 6144;     // fallback f32
    float* part = ws + 8192;   // 131072 float4 = 2MB

    const size_t needed = (size_t)8192 * 4 + (size_t)131072 * 16;
    if (ws_size >= needed) {
        k_reduce_p1<<<1024, 256, 0, stream>>>((const float4*)k, (const float4*)v,
                                              (float4*)part);
        k_finish<<<32, 256, 0, stream>>>((const float4*)part, ls,
                                         (float4*)k2b, v2b);
        k_attn_mfma<<<4096, 256, 0, stream>>>((const float4*)q, (const float4*)mask,
                                              (const float4*)k2b, (const float4*)v2b,
                                              (float*)d_out);
    } else {
        hipMemsetAsync(ws, 0, 4096 * sizeof(float), stream);
        k_reduce_atomic<<<2048, 256, 0, stream>>>((const float4*)k, (const float4*)v,
                                                  ksum, vsum);
        k_prep<<<1, 256, 0, stream>>>(ksum, vsum, ls, k2, v2);
        k_attn<<<2048, 256, 0, stream>>>((const float4*)q, (const float2*)mask,
                                         (const float4*)k2, (const float4*)v2,
                                         (float4*)d_out);
    }
}